// Round 6
// baseline (626.332 us; speedup 1.0000x reference)
//
#include <hip/hip_runtime.h>
#include <math.h>

typedef unsigned short u16;
typedef unsigned int   u32;
typedef short bf8v __attribute__((ext_vector_type(8)));   // 8 bf16 in 4 VGPRs
typedef float f4v  __attribute__((ext_vector_type(4)));

static constexpr int B_=4, C_=256, K_=5, D_=256, N_=4096, IT_=4;
static constexpr float EPS_=1e-5f;
// prep0 block layout (256 threads)
static constexpr int P0_MISC=96, P0_UQ=97, P0_FG=98, P0_GRID=103;
// base block layout (512 threads)
static constexpr int BT_QP=256, BT_TR=276, BT_GRID=404;

__device__ __forceinline__ float bf2f(u16 u){ u32 x=((u32)u)<<16; float f; __builtin_memcpy(&f,&x,4); return f; }
__device__ __forceinline__ float bflo(u32 u){ u32 x=u<<16; float f; __builtin_memcpy(&f,&x,4); return f; }
__device__ __forceinline__ float bfhi(u32 u){ u32 x=u&0xffff0000u; float f; __builtin_memcpy(&f,&x,4); return f; }
__device__ __forceinline__ u16 f2bf(float f){ u32 x; __builtin_memcpy(&x,&f,4); u32 r=x+0x7fffu+((x>>16)&1u); return (u16)(r>>16); }
__device__ __forceinline__ float ldin(const void* p, size_t i, int f){
  return f ? ((const float*)p)[i] : bf2f(((const u16*)p)[i]);
}
__device__ __forceinline__ void stout(void* p, size_t i, float v, int f){
  if (f) ((float*)p)[i]=v; else ((u16*)p)[i]=f2bf(v);
}
// XOR-swizzled LDS index (u16 units)
__device__ __forceinline__ int sw16(int row,int col){
  return row*256 + ((((col>>3)^(row&7))<<3) | (col&7));
}

// ---- 256-thread (4-wave) reductions ----
__device__ __forceinline__ void breduce4(float&a,float&b,float&c,float&d,float* red){
  #pragma unroll
  for(int o=32;o>0;o>>=1){
    a+=__shfl_down(a,o,64); b+=__shfl_down(b,o,64);
    c+=__shfl_down(c,o,64); d+=__shfl_down(d,o,64);
  }
  int w=threadIdx.x>>6;
  __syncthreads();
  if((threadIdx.x&63)==0){ red[w]=a; red[4+w]=b; red[8+w]=c; red[12+w]=d; }
  __syncthreads();
  a=red[0]+red[1]+red[2]+red[3];
  b=red[4]+red[5]+red[6]+red[7];
  c=red[8]+red[9]+red[10]+red[11];
  d=red[12]+red[13]+red[14]+red[15];
}
// ---- 1024-thread (16-wave) reduction ----
__device__ __forceinline__ void breduce4_16(float&a,float&b,float&c,float&d,float* red){
  #pragma unroll
  for(int o=32;o>0;o>>=1){
    a+=__shfl_down(a,o,64); b+=__shfl_down(b,o,64);
    c+=__shfl_down(c,o,64); d+=__shfl_down(d,o,64);
  }
  int w=threadIdx.x>>6;
  __syncthreads();
  if((threadIdx.x&63)==0){ red[w]=a; red[16+w]=b; red[32+w]=c; red[48+w]=d; }
  __syncthreads();
  a=0;b=0;c=0;d=0;
  #pragma unroll
  for(int i=0;i<16;++i){ a+=red[i]; b+=red[16+i]; c+=red[32+i]; d+=red[48+i]; }
}

// ---- inline dtype probe ----
__device__ __forceinline__ int probe_f(const void* feat, float* red){
  const u32* p=(const u32*)feat;
  int t=threadIdx.x; int bad=0;
  #pragma unroll
  for(int s=0;s<8;++s){
    u32 wd=p[t+s*256];
    float lo=bf2f((u16)(wd&0xffffu));
    if(!(fabsf(lo)<1e6f)) bad++;
  }
  float bb=(float)bad, z1=0,z2=0,z3=0;
  breduce4(bb,z1,z2,z3,red);
  return (bb>=16.f)?1:0;
}

// ---- prep0 (256 threads) ----
__global__ void prep0_kernel(const void* feat,
    const void* kW, const void* vW, const void* mW,
    const void* mu, const void* lsig, const void* noise,
    const void* gW, const void* gb_, const void* mg,
    const void* mb_, const void* mbias, const void* mask,
    int* flag, int* cnt, float* slot, float* gvec,
    u16* Wkb, u16* Wvb, u16* Wgb,
    float* Uvec, float* Qs, float* fg, void* out)
{
  __shared__ float redp[16];
  int bid=blockIdx.x;
  int t=threadIdx.x;
  int f=probe_f(feat, redp);
  if(bid==0 && t==0) *flag=f;
  __syncthreads();
  if(bid<P0_MISC){
    int which=bid>>5;           // 0:k 1:v 2:g
    int base=(bid&31)*2048;
    if(which==0){
      #pragma unroll
      for(int s=0;s<8;++s){ int e=base+s*256+t; Wkb[e]=f2bf(ldin(kW,e,f)); }
    } else if(which==1){
      #pragma unroll
      for(int s=0;s<8;++s){ int e=base+s*256+t; Wvb[e]=f2bf(ldin(vW,e,f)); }
    } else {
      #pragma unroll
      for(int s=0;s<8;++s){ int e=base+s*256+t; int c=e&255; Wgb[e]=f2bf(ldin(mg,c,f)*ldin(mW,e,f)); }
    }
    return;
  }
  if(bid==P0_MISC){
    cnt[t]=0; cnt[t+256]=0;     // 16 iters*batches x 32-int (128B) padded counters
    #pragma unroll
    for(int s=0;s<20;++s){ int e=s*256+t; int d=e&255;
      slot[e]=ldin(mu,d,f)+expf(ldin(lsig,d,f))*ldin(noise,e,f); }
    #pragma unroll
    for(int s=0;s<3;++s){ int e=s*256+t;
      int c=e&255, sel=e>>8;
      float v;
      if(sel==0)      v=ldin(gW,c*4+0,f)-ldin(gW,c*4+2,f);
      else if(sel==1) v=ldin(gW,c*4+1,f)-ldin(gW,c*4+3,f);
      else            v=ldin(gb_,c,f);
      gvec[e]=v;
    }
    return;
  }
  __shared__ float s_a[256], s_b[256], s_c[256];
  if(bid==P0_UQ){
    __shared__ float s_mg[256], s_mb[256];
    s_a[t]=ldin(gW,t*4+0,f)-ldin(gW,t*4+2,f);
    s_b[t]=ldin(gW,t*4+1,f)-ldin(gW,t*4+3,f);
    s_c[t]=ldin(gb_,t,f);
    s_mg[t]=ldin(mg,t,f);
    s_mb[t]=ldin(mb_,t,f);
    __syncthreads();
    float u1=0,u2=0,u3=0,gw=0,bw=0;
    if(f){
      const float4* rp=(const float4*)mW + (size_t)t*64;
      #pragma unroll 8
      for(int j=0;j<64;++j){
        float4 v4=rp[j]; int c=j*4;
        float m0=v4.x,m1=v4.y,m2=v4.z,m3=v4.w;
        float w0=s_mg[c]*m0, w1=s_mg[c+1]*m1, w2=s_mg[c+2]*m2, w3=s_mg[c+3]*m3;
        u1+=s_a[c]*w0+s_a[c+1]*w1+s_a[c+2]*w2+s_a[c+3]*w3;
        u2+=s_b[c]*w0+s_b[c+1]*w1+s_b[c+2]*w2+s_b[c+3]*w3;
        u3+=s_c[c]*w0+s_c[c+1]*w1+s_c[c+2]*w2+s_c[c+3]*w3;
        gw+=w0+w1+w2+w3;
        bw+=s_mb[c]*m0+s_mb[c+1]*m1+s_mb[c+2]*m2+s_mb[c+3]*m3;
      }
    } else {
      const bf8v* rp=(const bf8v*)((const u16*)mW + (size_t)t*256);
      #pragma unroll 8
      for(int j=0;j<32;++j){
        bf8v v8=rp[j]; int c=j*8;
        #pragma unroll
        for(int e=0;e<8;++e){
          float mwv=bf2f((u16)(unsigned short)v8[e]);
          float wg=s_mg[c+e]*mwv;
          u1+=s_a[c+e]*wg; u2+=s_b[c+e]*wg; u3+=s_c[c+e]*wg; gw+=wg;
          bw+=s_mb[c+e]*mwv;
        }
      }
    }
    Uvec[t]=u1; Uvec[256+t]=u2; Uvec[512+t]=u3; Uvec[768+t]=gw;
    Uvec[1024+t]=bw+ldin(mbias,t,f);
    float a=s_a[t], b=s_b[t], cc=s_c[t];
    float s0=a*a,s1=b*b,s2=cc*cc,s3=a*b; breduce4(s0,s1,s2,s3,redp);
    float s4=a*cc,s5=b*cc,s6=a,s7=b;     breduce4(s4,s5,s6,s7,redp);
    float s8=cc,z1=0,z2=0,z3=0;          breduce4(s8,z1,z2,z3,redp);
    if(t==0){
      Qs[0]=s0; Qs[1]=s1; Qs[2]=s2; Qs[3]=s3; Qs[4]=s4; Qs[5]=s5;
      Qs[6]=s6*(1.f/256.f); Qs[7]=s7*(1.f/256.f); Qs[8]=s8*(1.f/256.f);
    }
  } else {
    int k=bid-P0_FG;
    float sx=0,sy=0,sm=0;
    #pragma unroll
    for(int s=0;s<16;++s){
      int p=t+s*256;
      float m=ldin(mask,(size_t)k*N_+p,f);
      int i=p>>6, j=p&63;
      float x=(2*j+1)*(1.0f/64.0f)-1.0f;
      float y=(2*i+1)*(1.0f/64.0f)-1.0f;
      sx+=x*m; sy+=y*m; sm+=m;
    }
    float d=0;
    breduce4(sx,sy,sm,d,redp);
    if(t==0){
      float inv=1.0f/(sm+1e-5f);
      float fx=sx*inv, fy=sy*inv;
      fg[k*2]=fx; fg[k*2+1]=fy;
      for(int b=0;b<B_;++b){
        stout(out, 5120+(b*K_+k)*2+0, fx, f);
        stout(out, 5120+(b*K_+k)*2+1, fy, f);
      }
    }
  }
}

// ---- base (unchanged) ----
__global__ void __launch_bounds__(512,2) base_kernel(const int* flag, const void* feat, const void* ng, const void* nb,
    const u16* Wkb, const u16* Wvb, const u16* Wgb, const float* gvec,
    float* scal, u16* PkT, u16* Pvb,
    const float* slot, const void* qg, const void* qb_, const void* qW,
    const void* rW, const void* Wih, const void* Whh,
    float* WqT, float* WrT, float* WihT, float* WhhT,
    float* qbuf)
{
  extern __shared__ u16 smem[];          // 64 KiB dynamic
  u16* bufA = smem;
  u16* bufB = smem + 16384;
  int t=threadIdx.x, f=*flag;
  if(blockIdx.x>=BT_TR){
    float (*tile)[65] = (float(*)[65])smem;
    int b2=blockIdx.x-BT_TR;
    const void* src; float* dst; int OS;
    if(b2<16){ src=qW; dst=WqT; OS=256; }
    else if(b2<32){ src=rW; dst=WrT; OS=256; b2-=16; }
    else if(b2<80){ src=Wih; dst=WihT; OS=768; b2-=32; }
    else { src=Whh; dst=WhhT; OS=768; b2-=80; }
    int r0=(b2>>2)*64, c0=(b2&3)*64;
    int lane=t&63, wv=t>>6;
    #pragma unroll
    for(int it=0;it<8;++it){
      int i=wv*8+it;
      tile[i][lane]=ldin(src,(size_t)(r0+i)*256+c0+lane,f);
    }
    __syncthreads();
    #pragma unroll
    for(int it=0;it<8;++it){
      int i=wv*8+it;
      dst[(size_t)(c0+i)*OS + r0 + lane] = tile[lane][i];
    }
    return;
  }
  if(blockIdx.x>=BT_QP){
    float* Lq =(float*)smem;
    float* pp =(float*)smem+256;
    float* red=(float*)smem+768;
    int bk=blockIdx.x-BT_QP;
    int tt=t&255, hh=t>>8, w=t>>6;
    float x=slot[bk*256+tt];
    float s=x, s2=x*x;
    #pragma unroll
    for(int o=32;o>0;o>>=1){ s+=__shfl_down(s,o,64); s2+=__shfl_down(s2,o,64); }
    if((t&63)==0){ red[w]=s; red[8+w]=s2; }
    __syncthreads();
    s=0; s2=0;
    #pragma unroll
    for(int i=0;i<8;++i){ s+=red[i]; s2+=red[8+i]; }
    float m=s*(1.f/512.f), v=s2*(1.f/512.f)-m*m;
    float lq=(x-m)*rsqrtf(v+EPS_)*ldin(qg,tt,f)+ldin(qb_,tt,f);
    if(hh==0) Lq[tt]=lq;
    __syncthreads();
    float acc=0; int cb=hh*128;
    if(f){
      const float4* rp=(const float4*)qW + ((size_t)tt*256+cb)/4;
      #pragma unroll 8
      for(int j=0;j<32;++j){
        float4 v4=rp[j]; int c=cb+j*4;
        acc+=Lq[c]*v4.x+Lq[c+1]*v4.y+Lq[c+2]*v4.z+Lq[c+3]*v4.w;
      }
    } else {
      const bf8v* rp=(const bf8v*)((const u16*)qW + (size_t)tt*256+cb);
      #pragma unroll 8
      for(int j=0;j<16;++j){
        bf8v v8=rp[j]; int c=cb+j*8;
        #pragma unroll
        for(int e=0;e<8;++e) acc+=Lq[c+e]*bf2f((u16)(unsigned short)v8[e]);
      }
    }
    pp[hh*256+tt]=acc;
    __syncthreads();
    if(hh==0) qbuf[bk*256+tt]=pp[tt]+pp[256+tt];
    return;
  }
  int w=t>>6, l=t&63;
  int quad=l>>4, m=l&15;
  int row0=blockIdx.x*64;
  {
    float g0=ldin(ng,4*l+0,f), g1=ldin(ng,4*l+1,f), g2=ldin(ng,4*l+2,f), g3=ldin(ng,4*l+3,f);
    float b0=ldin(nb,4*l+0,f), b1=ldin(nb,4*l+1,f), b2=ldin(nb,4*l+2,f), b3=ldin(nb,4*l+3,f);
    #pragma unroll
    for(int r8=0;r8<8;++r8){
      int row=8*w+r8;
      float x0,x1,x2,x3;
      if(f){
        float4 v4=((const float4*)feat)[(size_t)(row0+row)*64+l];
        x0=v4.x; x1=v4.y; x2=v4.z; x3=v4.w;
      } else {
        ushort4 uu=((const ushort4*)feat)[(size_t)(row0+row)*64+l];
        x0=bf2f(uu.x); x1=bf2f(uu.y); x2=bf2f(uu.z); x3=bf2f(uu.w);
      }
      float s=x0+x1+x2+x3, s2=x0*x0+x1*x1+x2*x2+x3*x3;
      #pragma unroll
      for(int o=32;o>0;o>>=1){ s+=__shfl_xor(s,o,64); s2+=__shfl_xor(s2,o,64); }
      float mm=s*(1.f/256.f), inv=rsqrtf(s2*(1.f/256.f)-mm*mm+EPS_);
      ushort4 o4=make_ushort4(f2bf((x0-mm)*inv*g0+b0), f2bf((x1-mm)*inv*g1+b1),
                              f2bf((x2-mm)*inv*g2+b2), f2bf((x3-mm)*inv*g3+b3));
      *(ushort4*)&bufA[sw16(row,4*l)]=o4;
    }
  }
  __syncthreads();
  {
    f4v ack[4][2], acv[4][2];
    #pragma unroll
    for(int rt=0;rt<4;++rt)
      #pragma unroll
      for(int i=0;i<2;++i){ ack[rt][i]=(f4v){0.f,0.f,0.f,0.f}; acv[rt][i]=(f4v){0.f,0.f,0.f,0.f}; }
    #pragma unroll
    for(int kk=0;kk<8;++kk){
      int kcol=kk*32+quad*8;
      bf8v af[4];
      #pragma unroll
      for(int rt=0;rt<4;++rt) af[rt]=*(bf8v*)&bufA[sw16(rt*16+m,kcol)];
      #pragma unroll
      for(int i=0;i<2;++i){
        int n=w*32+16*i+m;
        bf8v bk=*(const bf8v*)(Wkb+(size_t)n*256+kcol);
        bf8v bv=*(const bf8v*)(Wvb+(size_t)n*256+kcol);
        #pragma unroll
        for(int rt=0;rt<4;++rt){
          ack[rt][i]=__builtin_amdgcn_mfma_f32_16x16x32_bf16(af[rt],bk,ack[rt][i],0,0,0);
          acv[rt][i]=__builtin_amdgcn_mfma_f32_16x16x32_bf16(af[rt],bv,acv[rt][i],0,0,0);
        }
      }
    }
    #pragma unroll
    for(int rt=0;rt<4;++rt)
      #pragma unroll
      for(int i=0;i<2;++i){
        int n=w*32+16*i+m;
        #pragma unroll
        for(int r=0;r<4;++r)
          bufB[sw16(rt*16+quad*4+r,n)]=f2bf(ack[rt][i][r]);
      }
    __syncthreads();
    #pragma unroll
    for(int rt=0;rt<4;++rt)
      #pragma unroll
      for(int i=0;i<2;++i){
        int n=w*32+16*i+m;
        #pragma unroll
        for(int r=0;r<4;++r)
          bufA[sw16(rt*16+quad*4+r,n)]=f2bf(acv[rt][i][r]);
      }
  }
  __syncthreads();
  {
    float gA0=gvec[l], gA1=gvec[l+64], gA2=gvec[l+128], gA3=gvec[l+192];
    float gB0=gvec[256+l], gB1=gvec[256+l+64], gB2=gvec[256+l+128], gB3=gvec[256+l+192];
    float gC0=gvec[512+l], gC1=gvec[512+l+64], gC2=gvec[512+l+128], gC3=gvec[512+l+192];
    for(int r8=0;r8<8;++r8){
      int row=8*w+r8;
      float k0=bf2f(bufB[sw16(row,l)]),     k1=bf2f(bufB[sw16(row,l+64)]),
            k2=bf2f(bufB[sw16(row,l+128)]), k3=bf2f(bufB[sw16(row,l+192)]);
      float x0=bf2f(bufA[sw16(row,l)]),     x1=bf2f(bufA[sw16(row,l+64)]),
            x2=bf2f(bufA[sw16(row,l+128)]), x3=bf2f(bufA[sw16(row,l+192)]);
      float v0=k0+k1+k2+k3;
      float v1=k0*k0+k1*k1+k2*k2+k3*k3;
      float v2=k0*gA0+k1*gA1+k2*gA2+k3*gA3;
      float v3=k0*gB0+k1*gB1+k2*gB2+k3*gB3;
      float v4=k0*gC0+k1*gC1+k2*gC2+k3*gC3;
      float v5=x0+x1+x2+x3;
      float v6=x0*x0+x1*x1+x2*x2+x3*x3;
      float v7=x0*gA0+x1*gA1+x2*gA2+x3*gA3;
      float v8=x0*gB0+x1*gB1+x2*gB2+x3*gB3;
      float v9=x0*gC0+x1*gC1+x2*gC2+x3*gC3;
      #pragma unroll
      for(int o=32;o>0;o>>=1){
        v0+=__shfl_down(v0,o,64); v1+=__shfl_down(v1,o,64); v2+=__shfl_down(v2,o,64);
        v3+=__shfl_down(v3,o,64); v4+=__shfl_down(v4,o,64); v5+=__shfl_down(v5,o,64);
        v6+=__shfl_down(v6,o,64); v7+=__shfl_down(v7,o,64); v8+=__shfl_down(v8,o,64);
        v9+=__shfl_down(v9,o,64);
      }
      if(l==0){
        float* sc=scal+(size_t)(row0+row)*10;
        sc[0]=v0; sc[1]=v1; sc[2]=v2; sc[3]=v3; sc[4]=v4;
        sc[5]=v5; sc[6]=v6; sc[7]=v7; sc[8]=v8; sc[9]=v9;
      }
    }
  }
  {
    f4v apk[4][2], apv[4][2];
    #pragma unroll
    for(int rt=0;rt<4;++rt)
      #pragma unroll
      for(int i=0;i<2;++i){ apk[rt][i]=(f4v){0.f,0.f,0.f,0.f}; apv[rt][i]=(f4v){0.f,0.f,0.f,0.f}; }
    #pragma unroll
    for(int kk=0;kk<8;++kk){
      int kcol=kk*32+quad*8;
      bf8v afk[4], afv[4];
      #pragma unroll
      for(int rt=0;rt<4;++rt){
        afk[rt]=*(bf8v*)&bufB[sw16(rt*16+m,kcol)];
        afv[rt]=*(bf8v*)&bufA[sw16(rt*16+m,kcol)];
      }
      #pragma unroll
      for(int i=0;i<2;++i){
        int n=w*32+16*i+m;
        bf8v bg=*(const bf8v*)(Wgb+(size_t)n*256+kcol);
        #pragma unroll
        for(int rt=0;rt<4;++rt){
          apk[rt][i]=__builtin_amdgcn_mfma_f32_16x16x32_bf16(afk[rt],bg,apk[rt][i],0,0,0);
          apv[rt][i]=__builtin_amdgcn_mfma_f32_16x16x32_bf16(afv[rt],bg,apv[rt][i],0,0,0);
        }
      }
    }
    #pragma unroll
    for(int rt=0;rt<4;++rt)
      #pragma unroll
      for(int i=0;i<2;++i){
        int d=w*32+16*i+m;
        *(ushort4*)(PkT+(size_t)d*16384+row0+rt*16+quad*4)=
          make_ushort4(f2bf(apk[rt][i][0]),f2bf(apk[rt][i][1]),f2bf(apk[rt][i][2]),f2bf(apk[rt][i][3]));
      }
    __syncthreads();
    #pragma unroll
    for(int rt=0;rt<4;++rt)
      #pragma unroll
      for(int i=0;i<2;++i){
        int d=w*32+16*i+m;
        #pragma unroll
        for(int r=0;r<4;++r)
          bufB[sw16(rt*16+quad*4+r,d)]=f2bf(apv[rt][i][r]);
      }
  }
  __syncthreads();
  #pragma unroll
  for(int r8=0;r8<8;++r8){
    int row=8*w+r8;
    ushort4 s4=*(ushort4*)&bufB[sw16(row,4*l)];
    *(ushort4*)(Pvb+(size_t)(row0+row)*256+4*l)=s4;
  }
}

// ---- fused per-iteration kernel. Sync fix: padded per-batch counters (128B apart),
//      producers atomicAdd once; consumers poll with ATOMIC LOAD (no RMW) + s_sleep backoff.
__global__ void __launch_bounds__(1024,1) iter_kernel(
    const int* flag, float* qbuf, const u16* PkT,
    const float* scal, const float* Qs, const float* Uvec, const float* fg, const void* mask,
    const u16* Pvb, float* logits, float* pmax, float* psum, float* updpart, float* sscp,
    int* cntb, int store_lg, int do_vis,
    float* slot, const float* WihT, const float* WhhT, const void* bih, const void* bhh,
    const void* rg, const void* rb_, const float* WrT, const void* rbias,
    const void* qg, const void* qb_, const float* WqT, void* out)
{
  extern __shared__ float sm[];
  float* q5  = sm;             // 1280
  float* un  = sm+1280;        // 10240
  float* lgs = sm+11520;       // 320
  float* ivs = sm+11840;       // 320
  float* mvs = sm+12160;       // 320
  float* qs5 = sm+12480;       // 40
  float* fgs = sm+12520;       // 10
  float* Qss = sm+12530;       // 9
  float* MSl = sm+12539;       // 5
  float* sredf=sm+12544;       // 160 = [8][5][4]
  int tid=threadIdx.x, f=*flag;
  int b=blockIdx.x>>6, ch=blockIdx.x&63;
  int w=tid>>6, l=tid&63;
  int n0=ch<<6;
  int* myc = cntb + b*32;      // one 128B line per batch
  // ================= attn chunk =================
  for(int p=tid;p<1280;p+=1024) q5[p]=qbuf[(size_t)b*1280+p];
  if(tid<10) fgs[tid]=fg[tid];
  if(tid<9)  Qss[tid]=Qs[tid];
  __syncthreads();
  if(w<8){
    for(int p=w;p<25;p+=8){
      int k=p/5, j=p%5;
      float s=q5[k*256+l]*Uvec[j*256+l]+q5[k*256+l+64]*Uvec[j*256+l+64]
             +q5[k*256+l+128]*Uvec[j*256+l+128]+q5[k*256+l+192]*Uvec[j*256+l+192];
      #pragma unroll
      for(int o=32;o>0;o>>=1) s+=__shfl_xor(s,o,64);
      if(l==0) qs5[k*8+j]=s;
    }
  }
  if(tid<512){
    int n=n0+l; size_t row=(size_t)b*N_+n;
    float dk0=0,dk1=0,dk2=0,dk3=0,dk4=0;
    int cbase=w*32;
    #pragma unroll 8
    for(int cc=0;cc<32;++cc){
      int c=cbase+cc;
      float pv=bf2f(PkT[(size_t)c*16384+row]);
      dk0+=pv*q5[c]; dk1+=pv*q5[256+c]; dk2+=pv*q5[512+c];
      dk3+=pv*q5[768+c]; dk4+=pv*q5[1024+c];
    }
    un[(w*5+0)*64+l]=dk0; un[(w*5+1)*64+l]=dk1; un[(w*5+2)*64+l]=dk2;
    un[(w*5+3)*64+l]=dk3; un[(w*5+4)*64+l]=dk4;
  }
  __syncthreads();
  if(tid<320){
    int k=tid>>6, nl=tid&63;
    float dot=0;
    #pragma unroll
    for(int j=0;j<8;++j) dot+=un[(j*5+k)*64+nl];
    int n2=n0+nl; size_t row2=(size_t)b*N_+n2;
    const float* sc=scal+row2*10;
    float rx=(2*(n2&63)+1)*(1.f/64.f)-1.f-fgs[2*k];
    float ry=(2*(n2>>6)+1)*(1.f/64.f)-1.f-fgs[2*k+1];
    float qge=rx*rx*Qss[0]+ry*ry*Qss[1]+Qss[2]+2.f*(rx*ry*Qss[3]+rx*Qss[4]+ry*Qss[5]);
    float mk=sc[0]*(1.f/256.f)+rx*Qss[6]+ry*Qss[7]+Qss[8];
    float sxk=sc[1]+2.f*(rx*sc[2]+ry*sc[3]+sc[4])+qge;
    float invK=rsqrtf(sxk*(1.f/256.f)-mk*mk+EPS_);
    float lg=invK*(dot+rx*qs5[k*8+0]+ry*qs5[k*8+1]+qs5[k*8+2]-mk*qs5[k*8+3])+qs5[k*8+4];
    float mval=ldin(mask,(size_t)k*N_+n2,f);
    lg=(mval==0.f)? -1e9f : lg*0.0625f;
    if(store_lg) logits[((size_t)(b*5+k))*N_+n2]=lg;
    lgs[tid]=lg;
    float mv=sc[5]*(1.f/256.f)+rx*Qss[6]+ry*Qss[7]+Qss[8];
    float sxv=sc[6]+2.f*(rx*sc[7]+ry*sc[8]+sc[9])+qge;
    mvs[tid]=mv;
    ivs[tid]=rsqrtf(sxv*(1.f/256.f)-mv*mv+EPS_);
  }
  __syncthreads();
  if(tid<64){
    #pragma unroll
    for(int k=0;k<5;++k){
      float v=lgs[k*64+tid];
      float M=v;
      #pragma unroll
      for(int o=32;o>0;o>>=1) M=fmaxf(M,__shfl_xor(M,o,64));
      float e=expf(v-M);
      #pragma unroll
      for(int o=32;o>0;o>>=1) e+=__shfl_xor(e,o,64);
      if(tid==0){ pmax[((size_t)(b*64+ch))*5+k]=M; psum[((size_t)(b*64+ch))*5+k]=e; MSl[k]=M; }
    }
  }
  __syncthreads();
  if(tid<512){
    float acc[5][4]={{0}};
    float swx[5]={0,0,0,0,0}, swy[5]={0,0,0,0,0}, sw[5]={0,0,0,0,0}, swm[5]={0,0,0,0,0};
    #pragma unroll 2
    for(int rr=0;rr<8;++rr){
      int nl=w*8+rr; int n2=n0+nl;
      size_t row=(size_t)b*N_+n2;
      uint2 pu=*(const uint2*)(Pvb+row*256+l*4);
      float px=bflo(pu.x), py=bfhi(pu.x), pz=bflo(pu.y), pw=bfhi(pu.y);
      int jx=n2&63, iy=n2>>6;
      #pragma unroll
      for(int k=0;k<5;++k){
        float wgt=expf(lgs[k*64+nl]-MSl[k])*ivs[k*64+nl];
        float rx=(2*jx+1)*(1.f/64.f)-1.f-fgs[2*k];
        float ry=(2*iy+1)*(1.f/64.f)-1.f-fgs[2*k+1];
        acc[k][0]+=wgt*px; acc[k][1]+=wgt*py; acc[k][2]+=wgt*pz; acc[k][3]+=wgt*pw;
        sw[k]+=wgt; swx[k]+=wgt*rx; swy[k]+=wgt*ry; swm[k]+=wgt*mvs[k*64+nl];
      }
    }
    #pragma unroll
    for(int k=0;k<5;++k)
      *(float4*)&un[(w*5+k)*256+l*4]=make_float4(acc[k][0],acc[k][1],acc[k][2],acc[k][3]);
    if(l==0){
      #pragma unroll
      for(int k=0;k<5;++k){
        sredf[(w*5+k)*4+0]=swx[k]; sredf[(w*5+k)*4+1]=swy[k];
        sredf[(w*5+k)*4+2]=sw[k];  sredf[(w*5+k)*4+3]=swm[k];
      }
    }
  }
  __syncthreads();
  for(int p=tid;p<1280;p+=1024){
    int k=p>>8, d=p&255;
    float v=0;
    #pragma unroll
    for(int j=0;j<8;++j) v+=un[(j*5+k)*256+d];
    updpart[((size_t)blockIdx.x*5+k)*256+d]=v;
  }
  if(tid<20){
    int kk=tid>>2, j=tid&3;
    float s=0;
    #pragma unroll
    for(int jj=0;jj<8;++jj) s+=sredf[(jj*5+kk)*4+j];
    sscp[((size_t)blockIdx.x*5+kk)*4+j]=s;
  }
  // ================= publish =================
  __threadfence();
  __syncthreads();
  if(tid==0) atomicAdd(myc,1);
  bool isgru=(ch<5);
  bool isvis=(do_vis && ch>=8 && ch<13);
  if(!isgru && !isvis) return;
  if(tid==0){
    // contention-free wait: plain atomic LOAD (no RMW) + sleep backoff
    while(__hip_atomic_load(myc, __ATOMIC_ACQUIRE, __HIP_MEMORY_SCOPE_AGENT) < 64)
      __builtin_amdgcn_s_sleep(8);
  }
  __syncthreads();
  __threadfence();
  // gru/vis LDS carve (aliases attn LDS; all attn reads complete)
  float* g_u  = sm;            // 256
  float* g_h  = sm+256;        // 256
  float* g_sn = sm+512;        // 256
  float* g_part=sm+768;        // [4][6][256]
  float* g_red =sm+6912;       // 64
  float* g_cvec=sm+6976;       // 4
  float* g_fch =sm+6980;       // 64
  float* g_MSg =sm+7044;       // 2
  int t=tid&255, g=tid>>8;
  if(isvis){
    int k2=ch-8, bk2=b*K_+k2;
    if(tid<64){
      float pm=pmax[((size_t)(b*64+tid))*5+k2];
      float ps=psum[((size_t)(b*64+tid))*5+k2];
      float M=pm;
      #pragma unroll
      for(int o=32;o>0;o>>=1) M=fmaxf(M,__shfl_xor(M,o,64));
      float e=ps*expf(pm-M);
      #pragma unroll
      for(int o=32;o>0;o>>=1) e+=__shfl_xor(e,o,64);
      if(tid==0){ g_MSg[0]=M; g_MSg[1]=1.0f/e; }
    }
    __syncthreads();
    float M=g_MSg[0], Sinv=g_MSg[1];
    float a[4]; float mn=1e30f, mx=-1e30f;
    #pragma unroll
    for(int s=0;s<4;++s){
      a[s]=expf(logits[(size_t)bk2*N_+tid+s*1024]-M)*Sinv;
      mn=fminf(mn,a[s]); mx=fmaxf(mx,a[s]);
    }
    #pragma unroll
    for(int o=32;o>0;o>>=1){ mn=fminf(mn,__shfl_down(mn,o,64)); mx=fmaxf(mx,__shfl_down(mx,o,64)); }
    int wv=tid>>6;
    __syncthreads();
    if((tid&63)==0){ g_red[wv]=mn; g_red[16+wv]=mx; }
    __syncthreads();
    mn=1e30f; mx=-1e30f;
    #pragma unroll
    for(int i=0;i<16;++i){ mn=fminf(mn,g_red[i]); mx=fmaxf(mx,g_red[16+i]); }
    float inv=1.0f/(mx-mn+1e-5f);
    #pragma unroll
    for(int s=0;s<4;++s) stout(out, 5160+(size_t)bk2*N_+tid+s*1024, (a[s]-mn)*inv, f);
    return;
  }
  // ================= GRU for (b, k=ch) =================
  int k=ch, bk=b*K_+k;
  if(tid<64){
    float pm=pmax[((size_t)(b*64+tid))*5+k];
    float ps=psum[((size_t)(b*64+tid))*5+k];
    float M=pm;
    #pragma unroll
    for(int o=32;o>0;o>>=1) M=fmaxf(M,__shfl_xor(M,o,64));
    float fc=expf(pm-M);
    g_fch[tid]=fc;
    float e=ps*fc;
    #pragma unroll
    for(int o=32;o>0;o>>=1) e+=__shfl_xor(e,o,64);
    if(tid==0){ g_MSg[0]=M; g_MSg[1]=1.0f/e; }
  }
  __syncthreads();
  float Sinv=g_MSg[1];
  float ua=0;
  {
    int ch0=g*16;
    #pragma unroll 4
    for(int ci=0;ci<16;++ci){ int c2=ch0+ci; ua += g_fch[c2]*updpart[(((size_t)(b*64+c2))*5+k)*256+t]; }
  }
  g_part[(g*6+0)*256+t]=ua;
  if(t<4){
    float s=0;
    #pragma unroll 4
    for(int ci=0;ci<16;++ci){ int c2=g*16+ci; s += g_fch[c2]*sscp[(((size_t)(b*64+c2))*5+k)*4+t]; }
    g_part[(g*6+1)*256+t]=s;
  }
  __syncthreads();
  if(g==0 && t<4) g_cvec[t]=g_part[(0*6+1)*256+t]+g_part[(1*6+1)*256+t]+g_part[(2*6+1)*256+t]+g_part[(3*6+1)*256+t];
  __syncthreads();
  if(g==0){
    float uu=g_part[(0*6+0)*256+t]+g_part[(1*6+0)*256+t]+g_part[(2*6+0)*256+t]+g_part[(3*6+0)*256+t];
    g_u[t]=(uu+g_cvec[0]*Uvec[t]+g_cvec[1]*Uvec[256+t]+g_cvec[2]*Uvec[512+t]-g_cvec[3]*Uvec[768+t])*Sinv
         +Uvec[1024+t];
    g_h[t]=slot[bk*256+t];
  }
  __syncthreads();
  float p0=0,p1=0,p2=0,p3=0,p4=0,p5=0;
  int c0=g*64;
  #pragma unroll 8
  for(int cc=0;cc<64;++cc){
    int c=c0+cc;
    float uc=g_u[c], hc=g_h[c];
    const float* wi=WihT+(size_t)c*768+t;
    const float* wh=WhhT+(size_t)c*768+t;
    p0+=uc*wi[0]; p1+=uc*wi[256]; p2+=uc*wi[512];
    p3+=hc*wh[0]; p4+=hc*wh[256]; p5+=hc*wh[512];
  }
  g_part[(g*6+0)*256+t]=p0; g_part[(g*6+1)*256+t]=p1; g_part[(g*6+2)*256+t]=p2;
  g_part[(g*6+3)*256+t]=p3; g_part[(g*6+4)*256+t]=p4; g_part[(g*6+5)*256+t]=p5;
  __syncthreads();
  float hn=0;
  if(g==0){
    float gi0=ldin(bih,t,f)+g_part[(0*6+0)*256+t]+g_part[(1*6+0)*256+t]+g_part[(2*6+0)*256+t]+g_part[(3*6+0)*256+t];
    float gi1=ldin(bih,256+t,f)+g_part[(0*6+1)*256+t]+g_part[(1*6+1)*256+t]+g_part[(2*6+1)*256+t]+g_part[(3*6+1)*256+t];
    float gi2=ldin(bih,512+t,f)+g_part[(0*6+2)*256+t]+g_part[(1*6+2)*256+t]+g_part[(2*6+2)*256+t]+g_part[(3*6+2)*256+t];
    float gh0=ldin(bhh,t,f)+g_part[(0*6+3)*256+t]+g_part[(1*6+3)*256+t]+g_part[(2*6+3)*256+t]+g_part[(3*6+3)*256+t];
    float gh1=ldin(bhh,256+t,f)+g_part[(0*6+4)*256+t]+g_part[(1*6+4)*256+t]+g_part[(2*6+4)*256+t]+g_part[(3*6+4)*256+t];
    float gh2=ldin(bhh,512+t,f)+g_part[(0*6+5)*256+t]+g_part[(1*6+5)*256+t]+g_part[(2*6+5)*256+t]+g_part[(3*6+5)*256+t];
    float r=1.f/(1.f+expf(-(gi0+gh0)));
    float z=1.f/(1.f+expf(-(gi1+gh1)));
    float nn=tanhf(gi2+r*gh2);
    hn=(1.f-z)*nn+z*g_h[t];
  }
  float s=hn, sq=hn*hn, za=0, zb=0;
  breduce4_16(s,sq,za,zb,g_red);
  if(g==0){
    float m=s*(1.f/256.f), var=sq*(1.f/256.f)-m*m;
    g_u[t]=(hn-m)*rsqrtf(var+EPS_)*ldin(rg,t,f)+ldin(rb_,t,f);
  }
  __syncthreads();
  float pr=0;
  #pragma unroll 8
  for(int cc=0;cc<64;++cc){ int c=c0+cc; pr+=g_u[c]*WrT[(size_t)c*256+t]; }
  g_part[(g*6+0)*256+t]=pr;
  __syncthreads();
  if(g==0){
    float acc=ldin(rbias,t,f)+g_h[t]+g_part[(0*6+0)*256+t]+g_part[(1*6+0)*256+t]+g_part[(2*6+0)*256+t]+g_part[(3*6+0)*256+t];
    slot[bk*256+t]=acc;
    stout(out, (size_t)bk*256+t, acc, f);
    g_sn[t]=acc;
  }
  __syncthreads();
  float xs=(g==0)? g_sn[t]:0.f;
  float xq=xs*xs, zc=0, zd=0;
  breduce4_16(xs,xq,zc,zd,g_red);
  if(g==0){
    float m=xs*(1.f/256.f), var=xq*(1.f/256.f)-m*m;
    g_u[t]=(g_sn[t]-m)*rsqrtf(var+EPS_)*ldin(qg,t,f)+ldin(qb_,t,f);
  }
  __syncthreads();
  float pq=0;
  #pragma unroll 8
  for(int cc=0;cc<64;++cc){ int c=c0+cc; pq+=g_u[c]*WqT[(size_t)c*256+t]; }
  g_part[(g*6+0)*256+t]=pq;
  __syncthreads();
  if(g==0){
    float qv=g_part[(0*6+0)*256+t]+g_part[(1*6+0)*256+t]+g_part[(2*6+0)*256+t]+g_part[(3*6+0)*256+t];
    qbuf[bk*256+t]=qv;
  }
}

extern "C" void kernel_launch(void* const* d_in, const int* in_sizes, int n_in,
                              void* d_out, int out_size, void* d_ws, size_t ws_size,
                              hipStream_t stream)
{
  const void* feat =d_in[0];  const void* mask =d_in[1];  const void* noise=d_in[2];
  const void* mu   =d_in[3];  const void* lsig =d_in[4];  const void* ng   =d_in[5];
  const void* nb   =d_in[6];  const void* gW   =d_in[7];  const void* gb_  =d_in[8];
  const void* kW   =d_in[9];  const void* vW   =d_in[10]; const void* mg   =d_in[11];
  const void* mb_  =d_in[12]; const void* mW   =d_in[13]; const void* mbias=d_in[14];
  const void* qg   =d_in[15]; const void* qb_  =d_in[16]; const void* qW   =d_in[17];
  const void* Wih  =d_in[18]; const void* Whh  =d_in[19]; const void* bih  =d_in[20];
  const void* bhh  =d_in[21]; const void* rg   =d_in[22]; const void* rb_  =d_in[23];
  const void* rW   =d_in[24]; const void* rbias=d_in[25];

  char* p=(char*)d_ws;
  auto alloc=[&](size_t bytes)->char*{ char* r=p; p+=(bytes+255)&~(size_t)255; return r; };
  int*   flag   =(int*)  alloc(256);
  int*   cnt    =(int*)  alloc(2048);   // 16 (iter,batch) slots x 32 ints (128B pad)
  float* fg     =(float*)alloc(64);
  float* slot   =(float*)alloc(5120*4);
  float* qbuf   =(float*)alloc(5120*4);
  float* logits =(float*)alloc((size_t)81920*4);
  float* pmax   =(float*)alloc(1280*4);
  float* psum   =(float*)alloc(1280*4);
  float* updpart=(float*)alloc((size_t)256*5*256*4);
  float* sscp   =(float*)alloc((size_t)256*5*4*4);
  float* WqT    =(float*)alloc((size_t)65536*4);
  float* WrT    =(float*)alloc((size_t)65536*4);
  float* WihT   =(float*)alloc((size_t)196608*4);
  float* WhhT   =(float*)alloc((size_t)196608*4);
  float* gvec   =(float*)alloc(768*4);
  float* Uvec   =(float*)alloc(1280*4);
  float* Qs     =(float*)alloc(64);
  float* scal   =(float*)alloc((size_t)163840*4);
  u16*   Wkb    =(u16*)  alloc((size_t)65536*2);
  u16*   Wvb    =(u16*)  alloc((size_t)65536*2);
  u16*   Wgb    =(u16*)  alloc((size_t)65536*2);
  u16*   PkT    =(u16*)  alloc((size_t)16384*256*2);
  u16*   Pvb    =(u16*)  alloc((size_t)16384*256*2);

  prep0_kernel<<<P0_GRID,256,0,stream>>>(feat,kW,vW,mW,mu,lsig,noise,gW,gb_,mg,
                                         mb_,mbias,mask,
                                         flag,cnt,slot,gvec,Wkb,Wvb,Wgb,
                                         Uvec,Qs,fg,d_out);
  base_kernel<<<BT_GRID,512,65536,stream>>>(flag,feat,ng,nb,Wkb,Wvb,Wgb,gvec,scal,PkT,Pvb,
                                            slot,qg,qb_,qW,rW,Wih,Whh,
                                            WqT,WrT,WihT,WhhT,qbuf);
  for(int it=0; it<IT_; ++it){
    int last=(it==IT_-1)?1:0;
    iter_kernel<<<256,1024,50816,stream>>>(flag,qbuf,PkT,scal,Qs,Uvec,fg,mask,Pvb,
                                           logits,pmax,psum,updpart,sscp,
                                           cnt+it*128,last,last,
                                           slot,WihT,WhhT,bih,bhh,rg,rb_,WrT,rbias,
                                           qg,qb_,WqT,d_out);
  }
}

// Round 7
// 335.267 us; speedup vs baseline: 1.8682x; 1.8682x over previous
//
#include <hip/hip_runtime.h>
#include <math.h>

typedef unsigned short u16;
typedef unsigned int   u32;
typedef short bf8v __attribute__((ext_vector_type(8)));   // 8 bf16 in 4 VGPRs
typedef float f4v  __attribute__((ext_vector_type(4)));

static constexpr int B_=4, C_=256, K_=5, D_=256, N_=4096, IT_=4;
static constexpr float EPS_=1e-5f;
// prep0 block layout (256 threads)
static constexpr int P0_MISC=96, P0_UQ=97, P0_FG=98, P0_GRID=103;
// base block layout (512 threads): 512 compute (32 rows each) + 20 qproj + 128 transpose
static constexpr int BT_QP=512, BT_TR=532, BT_GRID=660;

__device__ __forceinline__ float bf2f(u16 u){ u32 x=((u32)u)<<16; float f; __builtin_memcpy(&f,&x,4); return f; }
__device__ __forceinline__ float bflo(u32 u){ u32 x=u<<16; float f; __builtin_memcpy(&f,&x,4); return f; }
__device__ __forceinline__ float bfhi(u32 u){ u32 x=u&0xffff0000u; float f; __builtin_memcpy(&f,&x,4); return f; }
__device__ __forceinline__ u16 f2bf(float f){ u32 x; __builtin_memcpy(&x,&f,4); u32 r=x+0x7fffu+((x>>16)&1u); return (u16)(r>>16); }
__device__ __forceinline__ float ldin(const void* p, size_t i, int f){
  return f ? ((const float*)p)[i] : bf2f(((const u16*)p)[i]);
}
__device__ __forceinline__ void stout(void* p, size_t i, float v, int f){
  if (f) ((float*)p)[i]=v; else ((u16*)p)[i]=f2bf(v);
}
// XOR-swizzled LDS index (u16 units)
__device__ __forceinline__ int sw16(int row,int col){
  return row*256 + ((((col>>3)^(row&7))<<3) | (col&7));
}

// ---- 256-thread (4-wave) reductions ----
__device__ __forceinline__ void breduce4(float&a,float&b,float&c,float&d,float* red){
  #pragma unroll
  for(int o=32;o>0;o>>=1){
    a+=__shfl_down(a,o,64); b+=__shfl_down(b,o,64);
    c+=__shfl_down(c,o,64); d+=__shfl_down(d,o,64);
  }
  int w=threadIdx.x>>6;
  __syncthreads();
  if((threadIdx.x&63)==0){ red[w]=a; red[4+w]=b; red[8+w]=c; red[12+w]=d; }
  __syncthreads();
  a=red[0]+red[1]+red[2]+red[3];
  b=red[4]+red[5]+red[6]+red[7];
  c=red[8]+red[9]+red[10]+red[11];
  d=red[12]+red[13]+red[14]+red[15];
}
// ---- 1024-thread (16-wave) reduction ----
__device__ __forceinline__ void breduce4_16(float&a,float&b,float&c,float&d,float* red){
  #pragma unroll
  for(int o=32;o>0;o>>=1){
    a+=__shfl_down(a,o,64); b+=__shfl_down(b,o,64);
    c+=__shfl_down(c,o,64); d+=__shfl_down(d,o,64);
  }
  int w=threadIdx.x>>6;
  __syncthreads();
  if((threadIdx.x&63)==0){ red[w]=a; red[16+w]=b; red[32+w]=c; red[48+w]=d; }
  __syncthreads();
  a=0;b=0;c=0;d=0;
  #pragma unroll
  for(int i=0;i<16;++i){ a+=red[i]; b+=red[16+i]; c+=red[32+i]; d+=red[48+i]; }
}

// ---- inline dtype probe ----
__device__ __forceinline__ int probe_f(const void* feat, float* red){
  const u32* p=(const u32*)feat;
  int t=threadIdx.x; int bad=0;
  #pragma unroll
  for(int s=0;s<8;++s){
    u32 wd=p[t+s*256];
    float lo=bf2f((u16)(wd&0xffffu));
    if(!(fabsf(lo)<1e6f)) bad++;
  }
  float bb=(float)bad, z1=0,z2=0,z3=0;
  breduce4(bb,z1,z2,z3,red);
  return (bb>=16.f)?1:0;
}

// ---- prep0 (256 threads) ----
__global__ void prep0_kernel(const void* feat,
    const void* kW, const void* vW, const void* mW,
    const void* mu, const void* lsig, const void* noise,
    const void* gW, const void* gb_, const void* mg,
    const void* mb_, const void* mbias, const void* mask,
    int* flag, int* cnt, float* slot, float* gvec,
    u16* Wkb, u16* Wvb, u16* Wgb,
    float* Uvec, float* Qs, float* fg, void* out)
{
  __shared__ float redp[16];
  int bid=blockIdx.x;
  int t=threadIdx.x;
  int f=probe_f(feat, redp);
  if(bid==0 && t==0) *flag=f;
  __syncthreads();
  if(bid<P0_MISC){
    int which=bid>>5;           // 0:k 1:v 2:g
    int base=(bid&31)*2048;
    if(which==0){
      #pragma unroll
      for(int s=0;s<8;++s){ int e=base+s*256+t; Wkb[e]=f2bf(ldin(kW,e,f)); }
    } else if(which==1){
      #pragma unroll
      for(int s=0;s<8;++s){ int e=base+s*256+t; Wvb[e]=f2bf(ldin(vW,e,f)); }
    } else {
      #pragma unroll
      for(int s=0;s<8;++s){ int e=base+s*256+t; int c=e&255; Wgb[e]=f2bf(ldin(mg,c,f)*ldin(mW,e,f)); }
    }
    return;
  }
  if(bid==P0_MISC){
    if(t<16) cnt[t]=0;
    #pragma unroll
    for(int s=0;s<20;++s){ int e=s*256+t; int d=e&255;
      slot[e]=ldin(mu,d,f)+expf(ldin(lsig,d,f))*ldin(noise,e,f); }
    #pragma unroll
    for(int s=0;s<3;++s){ int e=s*256+t;
      int c=e&255, sel=e>>8;
      float v;
      if(sel==0)      v=ldin(gW,c*4+0,f)-ldin(gW,c*4+2,f);
      else if(sel==1) v=ldin(gW,c*4+1,f)-ldin(gW,c*4+3,f);
      else            v=ldin(gb_,c,f);
      gvec[e]=v;
    }
    return;
  }
  __shared__ float s_a[256], s_b[256], s_c[256];
  if(bid==P0_UQ){
    __shared__ float s_mg[256], s_mb[256];
    s_a[t]=ldin(gW,t*4+0,f)-ldin(gW,t*4+2,f);
    s_b[t]=ldin(gW,t*4+1,f)-ldin(gW,t*4+3,f);
    s_c[t]=ldin(gb_,t,f);
    s_mg[t]=ldin(mg,t,f);
    s_mb[t]=ldin(mb_,t,f);
    __syncthreads();
    float u1=0,u2=0,u3=0,gw=0,bw=0;
    if(f){
      const float4* rp=(const float4*)mW + (size_t)t*64;
      #pragma unroll 8
      for(int j=0;j<64;++j){
        float4 v4=rp[j]; int c=j*4;
        float m0=v4.x,m1=v4.y,m2=v4.z,m3=v4.w;
        float w0=s_mg[c]*m0, w1=s_mg[c+1]*m1, w2=s_mg[c+2]*m2, w3=s_mg[c+3]*m3;
        u1+=s_a[c]*w0+s_a[c+1]*w1+s_a[c+2]*w2+s_a[c+3]*w3;
        u2+=s_b[c]*w0+s_b[c+1]*w1+s_b[c+2]*w2+s_b[c+3]*w3;
        u3+=s_c[c]*w0+s_c[c+1]*w1+s_c[c+2]*w2+s_c[c+3]*w3;
        gw+=w0+w1+w2+w3;
        bw+=s_mb[c]*m0+s_mb[c+1]*m1+s_mb[c+2]*m2+s_mb[c+3]*m3;
      }
    } else {
      const bf8v* rp=(const bf8v*)((const u16*)mW + (size_t)t*256);
      #pragma unroll 8
      for(int j=0;j<32;++j){
        bf8v v8=rp[j]; int c=j*8;
        #pragma unroll
        for(int e=0;e<8;++e){
          float mwv=bf2f((u16)(unsigned short)v8[e]);
          float wg=s_mg[c+e]*mwv;
          u1+=s_a[c+e]*wg; u2+=s_b[c+e]*wg; u3+=s_c[c+e]*wg; gw+=wg;
          bw+=s_mb[c+e]*mwv;
        }
      }
    }
    Uvec[t]=u1; Uvec[256+t]=u2; Uvec[512+t]=u3; Uvec[768+t]=gw;
    Uvec[1024+t]=bw+ldin(mbias,t,f);
    float a=s_a[t], b=s_b[t], cc=s_c[t];
    float s0=a*a,s1=b*b,s2=cc*cc,s3=a*b; breduce4(s0,s1,s2,s3,redp);
    float s4=a*cc,s5=b*cc,s6=a,s7=b;     breduce4(s4,s5,s6,s7,redp);
    float s8=cc,z1=0,z2=0,z3=0;          breduce4(s8,z1,z2,z3,redp);
    if(t==0){
      Qs[0]=s0; Qs[1]=s1; Qs[2]=s2; Qs[3]=s3; Qs[4]=s4; Qs[5]=s5;
      Qs[6]=s6*(1.f/256.f); Qs[7]=s7*(1.f/256.f); Qs[8]=s8*(1.f/256.f);
    }
  } else {
    int k=bid-P0_FG;
    float sx=0,sy=0,sm=0;
    #pragma unroll
    for(int s=0;s<16;++s){
      int p=t+s*256;
      float m=ldin(mask,(size_t)k*N_+p,f);
      int i=p>>6, j=p&63;
      float x=(2*j+1)*(1.0f/64.0f)-1.0f;
      float y=(2*i+1)*(1.0f/64.0f)-1.0f;
      sx+=x*m; sy+=y*m; sm+=m;
    }
    float d=0;
    breduce4(sx,sy,sm,d,redp);
    if(t==0){
      float inv=1.0f/(sm+1e-5f);
      float fx=sx*inv, fy=sy*inv;
      fg[k*2]=fx; fg[k*2+1]=fy;
      for(int b=0;b<B_;++b){
        stout(out, 5120+(b*K_+k)*2+0, fx, f);
        stout(out, 5120+(b*K_+k)*2+1, fy, f);
      }
    }
  }
}

// ---- base: blocks [0,512): 32 rows/block, 512 threads, 32KB LDS -> 2 blocks/CU
//      (phase latency of co-resident blocks overlaps; weight traffic x2 but L2-served)
// ---- blocks [512,532): iter-0 q projection;  [532,660): 64x64 weight transposes
__global__ void __launch_bounds__(512,4) base_kernel(const int* flag, const void* feat, const void* ng, const void* nb,
    const u16* Wkb, const u16* Wvb, const u16* Wgb, const float* gvec,
    float* scal, u16* PkT, u16* Pvb,
    const float* slot, const void* qg, const void* qb_, const void* qW,
    const void* rW, const void* Wih, const void* Whh,
    float* WqT, float* WrT, float* WihT, float* WhhT,
    float* qbuf)
{
  extern __shared__ u16 smem[];          // 32 KiB dynamic
  u16* bufA = smem;                      // fnb -> vbL (32x256 bf16, swizzled)
  u16* bufB = smem + 8192;               // kbL -> Pv staging
  int t=threadIdx.x, f=*flag;
  if(blockIdx.x>=BT_TR){
    float (*tile)[65] = (float(*)[65])smem;   // 16.6KB < 32KB
    int b2=blockIdx.x-BT_TR;
    const void* src; float* dst; int OS;
    if(b2<16){ src=qW; dst=WqT; OS=256; }
    else if(b2<32){ src=rW; dst=WrT; OS=256; b2-=16; }
    else if(b2<80){ src=Wih; dst=WihT; OS=768; b2-=32; }
    else { src=Whh; dst=WhhT; OS=768; b2-=80; }
    int r0=(b2>>2)*64, c0=(b2&3)*64;
    int lane=t&63, wv=t>>6;
    #pragma unroll
    for(int it=0;it<8;++it){
      int i=wv*8+it;
      tile[i][lane]=ldin(src,(size_t)(r0+i)*256+c0+lane,f);
    }
    __syncthreads();
    #pragma unroll
    for(int it=0;it<8;++it){
      int i=wv*8+it;
      dst[(size_t)(c0+i)*OS + r0 + lane] = tile[lane][i];
    }
    return;
  }
  if(blockIdx.x>=BT_QP){
    float* Lq =(float*)smem;
    float* pp =(float*)smem+256;
    float* red=(float*)smem+768;
    int bk=blockIdx.x-BT_QP;
    int tt=t&255, hh=t>>8, w=t>>6;
    float x=slot[bk*256+tt];
    float s=x, s2=x*x;
    #pragma unroll
    for(int o=32;o>0;o>>=1){ s+=__shfl_down(s,o,64); s2+=__shfl_down(s2,o,64); }
    if((t&63)==0){ red[w]=s; red[8+w]=s2; }
    __syncthreads();
    s=0; s2=0;
    #pragma unroll
    for(int i=0;i<8;++i){ s+=red[i]; s2+=red[8+i]; }
    float m=s*(1.f/512.f), v=s2*(1.f/512.f)-m*m;   // each value counted twice
    float lq=(x-m)*rsqrtf(v+EPS_)*ldin(qg,tt,f)+ldin(qb_,tt,f);
    if(hh==0) Lq[tt]=lq;
    __syncthreads();
    float acc=0; int cb=hh*128;
    if(f){
      const float4* rp=(const float4*)qW + ((size_t)tt*256+cb)/4;
      #pragma unroll 8
      for(int j=0;j<32;++j){
        float4 v4=rp[j]; int c=cb+j*4;
        acc+=Lq[c]*v4.x+Lq[c+1]*v4.y+Lq[c+2]*v4.z+Lq[c+3]*v4.w;
      }
    } else {
      const bf8v* rp=(const bf8v*)((const u16*)qW + (size_t)tt*256+cb);
      #pragma unroll 8
      for(int j=0;j<16;++j){
        bf8v v8=rp[j]; int c=cb+j*8;
        #pragma unroll
        for(int e=0;e<8;++e) acc+=Lq[c+e]*bf2f((u16)(unsigned short)v8[e]);
      }
    }
    pp[hh*256+tt]=acc;
    __syncthreads();
    if(hh==0) qbuf[bk*256+tt]=pp[tt]+pp[256+tt];
    return;
  }
  int w=t>>6, l=t&63;
  int quad=l>>4, m=l&15;
  int row0=blockIdx.x*32;
  // ---- LN: 4 rows per wave ----
  {
    float g0=ldin(ng,4*l+0,f), g1=ldin(ng,4*l+1,f), g2=ldin(ng,4*l+2,f), g3=ldin(ng,4*l+3,f);
    float b0=ldin(nb,4*l+0,f), b1=ldin(nb,4*l+1,f), b2=ldin(nb,4*l+2,f), b3=ldin(nb,4*l+3,f);
    #pragma unroll
    for(int r4=0;r4<4;++r4){
      int row=4*w+r4;
      float x0,x1,x2,x3;
      if(f){
        float4 v4=((const float4*)feat)[(size_t)(row0+row)*64+l];
        x0=v4.x; x1=v4.y; x2=v4.z; x3=v4.w;
      } else {
        ushort4 uu=((const ushort4*)feat)[(size_t)(row0+row)*64+l];
        x0=bf2f(uu.x); x1=bf2f(uu.y); x2=bf2f(uu.z); x3=bf2f(uu.w);
      }
      float s=x0+x1+x2+x3, s2=x0*x0+x1*x1+x2*x2+x3*x3;
      #pragma unroll
      for(int o=32;o>0;o>>=1){ s+=__shfl_xor(s,o,64); s2+=__shfl_xor(s2,o,64); }
      float mm=s*(1.f/256.f), inv=rsqrtf(s2*(1.f/256.f)-mm*mm+EPS_);
      ushort4 o4=make_ushort4(f2bf((x0-mm)*inv*g0+b0), f2bf((x1-mm)*inv*g1+b1),
                              f2bf((x2-mm)*inv*g2+b2), f2bf((x3-mm)*inv*g3+b3));
      *(ushort4*)&bufA[sw16(row,4*l)]=o4;
    }
  }
  __syncthreads();
  // ---- pass1: [32 x 256] @ Wk/Wv -> kbL (bufB), vbL (regs -> bufA) ----
  {
    f4v ack[2][2], acv[2][2];
    #pragma unroll
    for(int rt=0;rt<2;++rt)
      #pragma unroll
      for(int i=0;i<2;++i){ ack[rt][i]=(f4v){0.f,0.f,0.f,0.f}; acv[rt][i]=(f4v){0.f,0.f,0.f,0.f}; }
    #pragma unroll
    for(int kk=0;kk<8;++kk){
      int kcol=kk*32+quad*8;
      bf8v af[2];
      #pragma unroll
      for(int rt=0;rt<2;++rt) af[rt]=*(bf8v*)&bufA[sw16(rt*16+m,kcol)];
      #pragma unroll
      for(int i=0;i<2;++i){
        int n=w*32+16*i+m;
        bf8v bk=*(const bf8v*)(Wkb+(size_t)n*256+kcol);
        bf8v bv=*(const bf8v*)(Wvb+(size_t)n*256+kcol);
        #pragma unroll
        for(int rt=0;rt<2;++rt){
          ack[rt][i]=__builtin_amdgcn_mfma_f32_16x16x32_bf16(af[rt],bk,ack[rt][i],0,0,0);
          acv[rt][i]=__builtin_amdgcn_mfma_f32_16x16x32_bf16(af[rt],bv,acv[rt][i],0,0,0);
        }
      }
    }
    #pragma unroll
    for(int rt=0;rt<2;++rt)
      #pragma unroll
      for(int i=0;i<2;++i){
        int n=w*32+16*i+m;
        #pragma unroll
        for(int r=0;r<4;++r)
          bufB[sw16(rt*16+quad*4+r,n)]=f2bf(ack[rt][i][r]);
      }
    __syncthreads();   // all bufA (fnb) reads done
    #pragma unroll
    for(int rt=0;rt<2;++rt)
      #pragma unroll
      for(int i=0;i<2;++i){
        int n=w*32+16*i+m;
        #pragma unroll
        for(int r=0;r<4;++r)
          bufA[sw16(rt*16+quad*4+r,n)]=f2bf(acv[rt][i][r]);
      }
  }
  __syncthreads();
  // ---- scalars: 10 per row (k: bufB, v: bufA), 4 rows/wave ----
  {
    float gA0=gvec[l], gA1=gvec[l+64], gA2=gvec[l+128], gA3=gvec[l+192];
    float gB0=gvec[256+l], gB1=gvec[256+l+64], gB2=gvec[256+l+128], gB3=gvec[256+l+192];
    float gC0=gvec[512+l], gC1=gvec[512+l+64], gC2=gvec[512+l+128], gC3=gvec[512+l+192];
    for(int r4=0;r4<4;++r4){
      int row=4*w+r4;
      float k0=bf2f(bufB[sw16(row,l)]),     k1=bf2f(bufB[sw16(row,l+64)]),
            k2=bf2f(bufB[sw16(row,l+128)]), k3=bf2f(bufB[sw16(row,l+192)]);
      float x0=bf2f(bufA[sw16(row,l)]),     x1=bf2f(bufA[sw16(row,l+64)]),
            x2=bf2f(bufA[sw16(row,l+128)]), x3=bf2f(bufA[sw16(row,l+192)]);
      float v0=k0+k1+k2+k3;
      float v1=k0*k0+k1*k1+k2*k2+k3*k3;
      float v2=k0*gA0+k1*gA1+k2*gA2+k3*gA3;
      float v3=k0*gB0+k1*gB1+k2*gB2+k3*gB3;
      float v4=k0*gC0+k1*gC1+k2*gC2+k3*gC3;
      float v5=x0+x1+x2+x3;
      float v6=x0*x0+x1*x1+x2*x2+x3*x3;
      float v7=x0*gA0+x1*gA1+x2*gA2+x3*gA3;
      float v8=x0*gB0+x1*gB1+x2*gB2+x3*gB3;
      float v9=x0*gC0+x1*gC1+x2*gC2+x3*gC3;
      #pragma unroll
      for(int o=32;o>0;o>>=1){
        v0+=__shfl_down(v0,o,64); v1+=__shfl_down(v1,o,64); v2+=__shfl_down(v2,o,64);
        v3+=__shfl_down(v3,o,64); v4+=__shfl_down(v4,o,64); v5+=__shfl_down(v5,o,64);
        v6+=__shfl_down(v6,o,64); v7+=__shfl_down(v7,o,64); v8+=__shfl_down(v8,o,64);
        v9+=__shfl_down(v9,o,64);
      }
      if(l==0){
        float* sc=scal+(size_t)(row0+row)*10;
        sc[0]=v0; sc[1]=v1; sc[2]=v2; sc[3]=v3; sc[4]=v4;
        sc[5]=v5; sc[6]=v6; sc[7]=v7; sc[8]=v8; sc[9]=v9;
      }
    }
  }
  // ---- pass2: kbL/vbL @ Wg -> PkT (direct), Pv (staged via bufB) ----
  {
    f4v apk[2][2], apv[2][2];
    #pragma unroll
    for(int rt=0;rt<2;++rt)
      #pragma unroll
      for(int i=0;i<2;++i){ apk[rt][i]=(f4v){0.f,0.f,0.f,0.f}; apv[rt][i]=(f4v){0.f,0.f,0.f,0.f}; }
    #pragma unroll
    for(int kk=0;kk<8;++kk){
      int kcol=kk*32+quad*8;
      bf8v afk[2], afv[2];
      #pragma unroll
      for(int rt=0;rt<2;++rt){
        afk[rt]=*(bf8v*)&bufB[sw16(rt*16+m,kcol)];
        afv[rt]=*(bf8v*)&bufA[sw16(rt*16+m,kcol)];
      }
      #pragma unroll
      for(int i=0;i<2;++i){
        int n=w*32+16*i+m;
        bf8v bg=*(const bf8v*)(Wgb+(size_t)n*256+kcol);
        #pragma unroll
        for(int rt=0;rt<2;++rt){
          apk[rt][i]=__builtin_amdgcn_mfma_f32_16x16x32_bf16(afk[rt],bg,apk[rt][i],0,0,0);
          apv[rt][i]=__builtin_amdgcn_mfma_f32_16x16x32_bf16(afv[rt],bg,apv[rt][i],0,0,0);
        }
      }
    }
    #pragma unroll
    for(int rt=0;rt<2;++rt)
      #pragma unroll
      for(int i=0;i<2;++i){
        int d=w*32+16*i+m;
        *(ushort4*)(PkT+(size_t)d*16384+row0+rt*16+quad*4)=
          make_ushort4(f2bf(apk[rt][i][0]),f2bf(apk[rt][i][1]),f2bf(apk[rt][i][2]),f2bf(apk[rt][i][3]));
      }
    __syncthreads();   // all bufB (kbL) reads done
    #pragma unroll
    for(int rt=0;rt<2;++rt)
      #pragma unroll
      for(int i=0;i<2;++i){
        int d=w*32+16*i+m;
        #pragma unroll
        for(int r=0;r<4;++r)
          bufB[sw16(rt*16+quad*4+r,d)]=f2bf(apv[rt][i][r]);
      }
  }
  __syncthreads();
  // ---- coalesced Pvb store (4 rows/wave) ----
  #pragma unroll
  for(int r4=0;r4<4;++r4){
    int row=4*w+r4;
    ushort4 s4=*(ushort4*)&bufB[sw16(row,4*l)];
    *(ushort4*)(Pvb+(size_t)(row0+row)*256+4*l)=s4;
  }
}

// ---- fused attn (512 threads): qsc inline + logits + chunk softmax + weighted Pv partials ----
__global__ void __launch_bounds__(512) attn_kernel(const int* flag, const float* qbuf, const u16* PkT,
    const float* scal, const float* Qs, const float* Uvec, const float* fg, const void* mask,
    const u16* Pvb, float* logits, float* pmax, float* psum, float* updpart, float* sscp,
    int store_lg)
{
  __shared__ float q5[1280];
  __shared__ float un[10240];
  __shared__ float lgs[320], ivs[320], mvs[320];
  __shared__ float qs5[40], fgs[10], Qss[9], MSl[5];
  __shared__ float sred[8][5][4];
  int tid=threadIdx.x, f=*flag;
  int b=blockIdx.x>>6, ch=blockIdx.x&63;
  int w=tid>>6, l=tid&63;
  int n0=ch<<6;
  for(int p=tid;p<1280;p+=512) q5[p]=qbuf[(size_t)b*1280+p];
  if(tid<10) fgs[tid]=fg[tid];
  if(tid<9)  Qss[tid]=Qs[tid];
  __syncthreads();
  // qsc inline
  for(int p=w;p<25;p+=8){
    int k=p/5, j=p%5;
    float s=q5[k*256+l]*Uvec[j*256+l]+q5[k*256+l+64]*Uvec[j*256+l+64]
           +q5[k*256+l+128]*Uvec[j*256+l+128]+q5[k*256+l+192]*Uvec[j*256+l+192];
    #pragma unroll
    for(int o=32;o>0;o>>=1) s+=__shfl_xor(s,o,64);
    if(l==0) qs5[k*8+j]=s;
  }
  {
    int n=n0+l; size_t row=(size_t)b*N_+n;
    float dk0=0,dk1=0,dk2=0,dk3=0,dk4=0;
    int cbase=w*32;
    #pragma unroll 8
    for(int cc=0;cc<32;++cc){
      int c=cbase+cc;
      float pv=bf2f(PkT[(size_t)c*16384+row]);
      dk0+=pv*q5[c]; dk1+=pv*q5[256+c]; dk2+=pv*q5[512+c];
      dk3+=pv*q5[768+c]; dk4+=pv*q5[1024+c];
    }
    un[(w*5+0)*64+l]=dk0; un[(w*5+1)*64+l]=dk1; un[(w*5+2)*64+l]=dk2;
    un[(w*5+3)*64+l]=dk3; un[(w*5+4)*64+l]=dk4;
  }
  __syncthreads();
  if(tid<320){
    int k=tid>>6, nl=tid&63;
    float dot=0;
    #pragma unroll
    for(int j=0;j<8;++j) dot+=un[(j*5+k)*64+nl];
    int n2=n0+nl; size_t row2=(size_t)b*N_+n2;
    const float* sc=scal+row2*10;
    float rx=(2*(n2&63)+1)*(1.f/64.f)-1.f-fgs[2*k];
    float ry=(2*(n2>>6)+1)*(1.f/64.f)-1.f-fgs[2*k+1];
    float qge=rx*rx*Qss[0]+ry*ry*Qss[1]+Qss[2]+2.f*(rx*ry*Qss[3]+rx*Qss[4]+ry*Qss[5]);
    float mk=sc[0]*(1.f/256.f)+rx*Qss[6]+ry*Qss[7]+Qss[8];
    float sxk=sc[1]+2.f*(rx*sc[2]+ry*sc[3]+sc[4])+qge;
    float invK=rsqrtf(sxk*(1.f/256.f)-mk*mk+EPS_);
    float lg=invK*(dot+rx*qs5[k*8+0]+ry*qs5[k*8+1]+qs5[k*8+2]-mk*qs5[k*8+3])+qs5[k*8+4];
    float mval=ldin(mask,(size_t)k*N_+n2,f);
    lg=(mval==0.f)? -1e9f : lg*0.0625f;
    if(store_lg) logits[((size_t)(b*5+k))*N_+n2]=lg;
    lgs[tid]=lg;
    float mv=sc[5]*(1.f/256.f)+rx*Qss[6]+ry*Qss[7]+Qss[8];
    float sxv=sc[6]+2.f*(rx*sc[7]+ry*sc[8]+sc[9])+qge;
    mvs[tid]=mv;
    ivs[tid]=rsqrtf(sxv*(1.f/256.f)-mv*mv+EPS_);
  }
  __syncthreads();
  if(tid<64){
    #pragma unroll
    for(int k=0;k<5;++k){
      float v=lgs[k*64+tid];
      float M=v;
      #pragma unroll
      for(int o=32;o>0;o>>=1) M=fmaxf(M,__shfl_xor(M,o,64));
      float e=expf(v-M);
      #pragma unroll
      for(int o=32;o>0;o>>=1) e+=__shfl_xor(e,o,64);
      if(tid==0){ pmax[((size_t)(b*64+ch))*5+k]=M; psum[((size_t)(b*64+ch))*5+k]=e; MSl[k]=M; }
    }
  }
  __syncthreads();
  {
    float acc[5][4]={{0}};
    float swx[5]={0,0,0,0,0}, swy[5]={0,0,0,0,0}, sw[5]={0,0,0,0,0}, swm[5]={0,0,0,0,0};
    #pragma unroll 2
    for(int rr=0;rr<8;++rr){
      int nl=w*8+rr; int n2=n0+nl;
      size_t row=(size_t)b*N_+n2;
      uint2 pu=*(const uint2*)(Pvb+row*256+l*4);
      float px=bflo(pu.x), py=bfhi(pu.x), pz=bflo(pu.y), pw=bfhi(pu.y);
      int jx=n2&63, iy=n2>>6;
      #pragma unroll
      for(int k=0;k<5;++k){
        float wgt=expf(lgs[k*64+nl]-MSl[k])*ivs[k*64+nl];
        float rx=(2*jx+1)*(1.f/64.f)-1.f-fgs[2*k];
        float ry=(2*iy+1)*(1.f/64.f)-1.f-fgs[2*k+1];
        acc[k][0]+=wgt*px; acc[k][1]+=wgt*py; acc[k][2]+=wgt*pz; acc[k][3]+=wgt*pw;
        sw[k]+=wgt; swx[k]+=wgt*rx; swy[k]+=wgt*ry; swm[k]+=wgt*mvs[k*64+nl];
      }
    }
    #pragma unroll
    for(int k=0;k<5;++k)
      *(float4*)&un[(w*5+k)*256+l*4]=make_float4(acc[k][0],acc[k][1],acc[k][2],acc[k][3]);
    if(l==0){
      #pragma unroll
      for(int k=0;k<5;++k){ sred[w][k][0]=swx[k]; sred[w][k][1]=swy[k];
                            sred[w][k][2]=sw[k];  sred[w][k][3]=swm[k]; }
    }
  }
  __syncthreads();
  for(int p=tid;p<1280;p+=512){
    int k=p>>8, d=p&255;
    float v=0;
    #pragma unroll
    for(int j=0;j<8;++j) v+=un[(j*5+k)*256+d];
    updpart[((size_t)blockIdx.x*5+k)*256+d]=v;
  }
  if(tid<20){
    int kk=tid>>2, j=tid&3;
    float s=0;
    #pragma unroll
    for(int jj=0;jj<8;++jj) s+=sred[jj][kk][j];
    sscp[((size_t)blockIdx.x*5+kk)*4+j]=s;
  }
}

// ---- GRU (blocks 0..19) + optional vis (blocks 20..39 when do_vis) ----
__global__ void __launch_bounds__(1024) gru_kernel(const int* flag, float* slot, const float* updpart,
    const float* sscp, const float* Uvec, const float* pmax, const float* psum, const float* logits,
    const float* WihT, const float* WhhT, const void* bih, const void* bhh,
    const void* rg, const void* rb_, const float* WrT, const void* rbias,
    const void* qg, const void* qb_, const float* WqT, float* qbuf,
    int do_vis, void* out)
{
  __shared__ float u[256], h[256], sn[256];
  __shared__ float part[4][6][256];
  __shared__ float red[64];
  __shared__ float cvec[4];
  __shared__ float fch[64];
  __shared__ float MSg[2];
  int tid=threadIdx.x, t=tid&255, g=tid>>8;
  int blk=blockIdx.x;
  int f=*flag;
  if(blk>=20){
    if(!do_vis) return;
    int bk2=blk-20, k2=bk2%K_, b2=bk2/K_;
    if(tid<64){
      float pm=pmax[((size_t)(b2*64+tid))*5+k2];
      float ps=psum[((size_t)(b2*64+tid))*5+k2];
      float M=pm;
      #pragma unroll
      for(int o=32;o>0;o>>=1) M=fmaxf(M,__shfl_xor(M,o,64));
      float e=ps*expf(pm-M);
      #pragma unroll
      for(int o=32;o>0;o>>=1) e+=__shfl_xor(e,o,64);
      if(tid==0){ MSg[0]=M; MSg[1]=1.0f/e; }
    }
    __syncthreads();
    float M=MSg[0], Sinv=MSg[1];
    float a[4]; float mn=1e30f, mx=-1e30f;
    #pragma unroll
    for(int s=0;s<4;++s){
      a[s]=expf(logits[(size_t)bk2*N_+tid+s*1024]-M)*Sinv;
      mn=fminf(mn,a[s]); mx=fmaxf(mx,a[s]);
    }
    #pragma unroll
    for(int o=32;o>0;o>>=1){ mn=fminf(mn,__shfl_down(mn,o,64)); mx=fmaxf(mx,__shfl_down(mx,o,64)); }
    int wv=tid>>6;
    __syncthreads();
    if((tid&63)==0){ red[wv]=mn; red[16+wv]=mx; }
    __syncthreads();
    mn=1e30f; mx=-1e30f;
    #pragma unroll
    for(int i=0;i<16;++i){ mn=fminf(mn,red[i]); mx=fmaxf(mx,red[16+i]); }
    float inv=1.0f/(mx-mn+1e-5f);
    #pragma unroll
    for(int s=0;s<4;++s) stout(out, 5160+(size_t)bk2*N_+tid+s*1024, (a[s]-mn)*inv, f);
    return;
  }
  int bk=blk, k=bk%K_, b=bk/K_;
  if(tid<64){
    float pm=pmax[((size_t)(b*64+tid))*5+k];
    float ps=psum[((size_t)(b*64+tid))*5+k];
    float M=pm;
    #pragma unroll
    for(int o=32;o>0;o>>=1) M=fmaxf(M,__shfl_xor(M,o,64));
    float fc=expf(pm-M);
    fch[tid]=fc;
    float e=ps*fc;
    #pragma unroll
    for(int o=32;o>0;o>>=1) e+=__shfl_xor(e,o,64);
    if(tid==0){ MSg[0]=M; MSg[1]=1.0f/e; }
  }
  __syncthreads();
  float Sinv=MSg[1];
  float ua=0;
  {
    int ch0=g*16;
    #pragma unroll 4
    for(int ci=0;ci<16;++ci){ int ch=ch0+ci; ua += fch[ch]*updpart[(((size_t)(b*64+ch))*5+k)*256+t]; }
  }
  part[g][0][t]=ua;
  if(t<4){
    float s=0;
    #pragma unroll 4
    for(int ci=0;ci<16;++ci){ int ch=g*16+ci; s += fch[ch]*sscp[(((size_t)(b*64+ch))*5+k)*4+t]; }
    part[g][1][t]=s;
  }
  __syncthreads();
  if(g==0 && t<4) cvec[t]=part[0][1][t]+part[1][1][t]+part[2][1][t]+part[3][1][t];
  __syncthreads();
  if(g==0){
    float uu=part[0][0][t]+part[1][0][t]+part[2][0][t]+part[3][0][t];
    u[t]=(uu+cvec[0]*Uvec[t]+cvec[1]*Uvec[256+t]+cvec[2]*Uvec[512+t]-cvec[3]*Uvec[768+t])*Sinv
         +Uvec[1024+t];
    h[t]=slot[bk*256+t];
  }
  __syncthreads();
  float p0=0,p1=0,p2=0,p3=0,p4=0,p5=0;
  int c0=g*64;
  #pragma unroll 8
  for(int cc=0;cc<64;++cc){
    int c=c0+cc;
    float uc=u[c], hc=h[c];
    const float* wi=WihT+(size_t)c*768+t;
    const float* wh=WhhT+(size_t)c*768+t;
    p0+=uc*wi[0]; p1+=uc*wi[256]; p2+=uc*wi[512];
    p3+=hc*wh[0]; p4+=hc*wh[256]; p5+=hc*wh[512];
  }
  part[g][0][t]=p0; part[g][1][t]=p1; part[g][2][t]=p2;
  part[g][3][t]=p3; part[g][4][t]=p4; part[g][5][t]=p5;
  __syncthreads();
  float hn=0;
  if(g==0){
    float gi0=ldin(bih,t,f)+part[0][0][t]+part[1][0][t]+part[2][0][t]+part[3][0][t];
    float gi1=ldin(bih,256+t,f)+part[0][1][t]+part[1][1][t]+part[2][1][t]+part[3][1][t];
    float gi2=ldin(bih,512+t,f)+part[0][2][t]+part[1][2][t]+part[2][2][t]+part[3][2][t];
    float gh0=ldin(bhh,t,f)+part[0][3][t]+part[1][3][t]+part[2][3][t]+part[3][3][t];
    float gh1=ldin(bhh,256+t,f)+part[0][4][t]+part[1][4][t]+part[2][4][t]+part[3][4][t];
    float gh2=ldin(bhh,512+t,f)+part[0][5][t]+part[1][5][t]+part[2][5][t]+part[3][5][t];
    float r=1.f/(1.f+expf(-(gi0+gh0)));
    float z=1.f/(1.f+expf(-(gi1+gh1)));
    float nn=tanhf(gi2+r*gh2);
    hn=(1.f-z)*nn+z*h[t];
  }
  float s=hn, sq=hn*hn, za=0, zb=0;
  breduce4_16(s,sq,za,zb,red);
  if(g==0){
    float m=s*(1.f/256.f), var=sq*(1.f/256.f)-m*m;
    u[t]=(hn-m)*rsqrtf(var+EPS_)*ldin(rg,t,f)+ldin(rb_,t,f);
  }
  __syncthreads();
  float pr=0;
  #pragma unroll 8
  for(int cc=0;cc<64;++cc){ int c=c0+cc; pr+=u[c]*WrT[(size_t)c*256+t]; }
  part[g][0][t]=pr;
  __syncthreads();
  if(g==0){
    float acc=ldin(rbias,t,f)+h[t]+part[0][0][t]+part[1][0][t]+part[2][0][t]+part[3][0][t];
    slot[bk*256+t]=acc;
    stout(out, (size_t)bk*256+t, acc, f);
    sn[t]=acc;
  }
  __syncthreads();
  float xs=(g==0)? sn[t]:0.f;
  float xq=xs*xs, zc=0, zd=0;
  breduce4_16(xs,xq,zc,zd,red);
  if(g==0){
    float m=xs*(1.f/256.f), var=xq*(1.f/256.f)-m*m;
    u[t]=(sn[t]-m)*rsqrtf(var+EPS_)*ldin(qg,t,f)+ldin(qb_,t,f);
  }
  __syncthreads();
  float pq=0;
  #pragma unroll 8
  for(int cc=0;cc<64;++cc){ int c=c0+cc; pq+=u[c]*WqT[(size_t)c*256+t]; }
  part[g][0][t]=pq;
  __syncthreads();
  if(g==0){
    float qv=part[0][0][t]+part[1][0][t]+part[2][0][t]+part[3][0][t];
    qbuf[bk*256+t]=qv;
  }
}

extern "C" void kernel_launch(void* const* d_in, const int* in_sizes, int n_in,
                              void* d_out, int out_size, void* d_ws, size_t ws_size,
                              hipStream_t stream)
{
  const void* feat =d_in[0];  const void* mask =d_in[1];  const void* noise=d_in[2];
  const void* mu   =d_in[3];  const void* lsig =d_in[4];  const void* ng   =d_in[5];
  const void* nb   =d_in[6];  const void* gW   =d_in[7];  const void* gb_  =d_in[8];
  const void* kW   =d_in[9];  const void* vW   =d_in[10]; const void* mg   =d_in[11];
  const void* mb_  =d_in[12]; const void* mW   =d_in[13]; const void* mbias=d_in[14];
  const void* qg   =d_in[15]; const void* qb_  =d_in[16]; const void* qW   =d_in[17];
  const void* Wih  =d_in[18]; const void* Whh  =d_in[19]; const void* bih  =d_in[20];
  const void* bhh  =d_in[21]; const void* rg   =d_in[22]; const void* rb_  =d_in[23];
  const void* rW   =d_in[24]; const void* rbias=d_in[25];

  char* p=(char*)d_ws;
  auto alloc=[&](size_t bytes)->char*{ char* r=p; p+=(bytes+255)&~(size_t)255; return r; };
  int*   flag   =(int*)  alloc(256);
  int*   cnt    =(int*)  alloc(2048);
  float* fg     =(float*)alloc(64);
  float* slot   =(float*)alloc(5120*4);
  float* qbuf   =(float*)alloc(5120*4);
  float* logits =(float*)alloc((size_t)81920*4);
  float* pmax   =(float*)alloc(1280*4);
  float* psum   =(float*)alloc(1280*4);
  float* updpart=(float*)alloc((size_t)256*5*256*4);
  float* sscp   =(float*)alloc((size_t)256*5*4*4);
  float* WqT    =(float*)alloc((size_t)65536*4);
  float* WrT    =(float*)alloc((size_t)65536*4);
  float* WihT   =(float*)alloc((size_t)196608*4);
  float* WhhT   =(float*)alloc((size_t)196608*4);
  float* gvec   =(float*)alloc(768*4);
  float* Uvec   =(float*)alloc(1280*4);
  float* Qs     =(float*)alloc(64);
  float* scal   =(float*)alloc((size_t)163840*4);
  u16*   Wkb    =(u16*)  alloc((size_t)65536*2);
  u16*   Wvb    =(u16*)  alloc((size_t)65536*2);
  u16*   Wgb    =(u16*)  alloc((size_t)65536*2);
  u16*   PkT    =(u16*)  alloc((size_t)16384*256*2);
  u16*   Pvb    =(u16*)  alloc((size_t)16384*256*2);

  prep0_kernel<<<P0_GRID,256,0,stream>>>(feat,kW,vW,mW,mu,lsig,noise,gW,gb_,mg,
                                         mb_,mbias,mask,
                                         flag,cnt,slot,gvec,Wkb,Wvb,Wgb,
                                         Uvec,Qs,fg,d_out);
  base_kernel<<<BT_GRID,512,32768,stream>>>(flag,feat,ng,nb,Wkb,Wvb,Wgb,gvec,scal,PkT,Pvb,
                                            slot,qg,qb_,qW,rW,Wih,Whh,
                                            WqT,WrT,WihT,WhhT,qbuf);
  for(int it=0; it<IT_; ++it){
    attn_kernel<<<B_*64,512,0,stream>>>(flag,qbuf,PkT,scal,Qs,Uvec,fg,mask,Pvb,
                                        logits,pmax,psum,updpart,sscp,(it==IT_-1)?1:0);
    int nb_g = (it==IT_-1)? 40 : 20;
    gru_kernel<<<nb_g,1024,0,stream>>>(flag,slot,updpart,sscp,Uvec,pmax,psum,logits,
                                       WihT,WhhT,bih,bhh,rg,rb_,WrT,rbias,
                                       qg,qb_,WqT,qbuf,(it==IT_-1)?1:0,d_out);
  }
}

// Round 8
// 321.122 us; speedup vs baseline: 1.9504x; 1.0441x over previous
//
#include <hip/hip_runtime.h>
#include <math.h>

typedef unsigned short u16;
typedef unsigned int   u32;
typedef short bf8v __attribute__((ext_vector_type(8)));   // 8 bf16 in 4 VGPRs
typedef float f4v  __attribute__((ext_vector_type(4)));

static constexpr int B_=4, C_=256, K_=5, D_=256, N_=4096, IT_=4;
static constexpr float EPS_=1e-5f;
// prep0 block layout (256 threads)
static constexpr int P0_MISC=96, P0_UQ=97, P0_FG=98, P0_GRID=103;
// base block layout (512 threads): 512 compute (32 rows each) + 20 qproj + 128 transpose
static constexpr int BT_QP=512, BT_TR=532, BT_GRID=660;

__device__ __forceinline__ float bf2f(u16 u){ u32 x=((u32)u)<<16; float f; __builtin_memcpy(&f,&x,4); return f; }
__device__ __forceinline__ float bflo(u32 u){ u32 x=u<<16; float f; __builtin_memcpy(&f,&x,4); return f; }
__device__ __forceinline__ float bfhi(u32 u){ u32 x=u&0xffff0000u; float f; __builtin_memcpy(&f,&x,4); return f; }
__device__ __forceinline__ u16 f2bf(float f){ u32 x; __builtin_memcpy(&x,&f,4); u32 r=x+0x7fffu+((x>>16)&1u); return (u16)(r>>16); }
__device__ __forceinline__ float ldin(const void* p, size_t i, int f){
  return f ? ((const float*)p)[i] : bf2f(((const u16*)p)[i]);
}
__device__ __forceinline__ void stout(void* p, size_t i, float v, int f){
  if (f) ((float*)p)[i]=v; else ((u16*)p)[i]=f2bf(v);
}
// XOR-swizzled LDS index (u16 units)
__device__ __forceinline__ int sw16(int row,int col){
  return row*256 + ((((col>>3)^(row&7))<<3) | (col&7));
}

// ---- 256-thread (4-wave) reductions ----
__device__ __forceinline__ void breduce4(float&a,float&b,float&c,float&d,float* red){
  #pragma unroll
  for(int o=32;o>0;o>>=1){
    a+=__shfl_down(a,o,64); b+=__shfl_down(b,o,64);
    c+=__shfl_down(c,o,64); d+=__shfl_down(d,o,64);
  }
  int w=threadIdx.x>>6;
  __syncthreads();
  if((threadIdx.x&63)==0){ red[w]=a; red[4+w]=b; red[8+w]=c; red[12+w]=d; }
  __syncthreads();
  a=red[0]+red[1]+red[2]+red[3];
  b=red[4]+red[5]+red[6]+red[7];
  c=red[8]+red[9]+red[10]+red[11];
  d=red[12]+red[13]+red[14]+red[15];
}
// ---- 1024-thread (16-wave) reduction ----
__device__ __forceinline__ void breduce4_16(float&a,float&b,float&c,float&d,float* red){
  #pragma unroll
  for(int o=32;o>0;o>>=1){
    a+=__shfl_down(a,o,64); b+=__shfl_down(b,o,64);
    c+=__shfl_down(c,o,64); d+=__shfl_down(d,o,64);
  }
  int w=threadIdx.x>>6;
  __syncthreads();
  if((threadIdx.x&63)==0){ red[w]=a; red[16+w]=b; red[32+w]=c; red[48+w]=d; }
  __syncthreads();
  a=0;b=0;c=0;d=0;
  #pragma unroll
  for(int i=0;i<16;++i){ a+=red[i]; b+=red[16+i]; c+=red[32+i]; d+=red[48+i]; }
}

// ---- inline dtype probe ----
__device__ __forceinline__ int probe_f(const void* feat, float* red){
  const u32* p=(const u32*)feat;
  int t=threadIdx.x; int bad=0;
  #pragma unroll
  for(int s=0;s<8;++s){
    u32 wd=p[t+s*256];
    float lo=bf2f((u16)(wd&0xffffu));
    if(!(fabsf(lo)<1e6f)) bad++;
  }
  float bb=(float)bad, z1=0,z2=0,z3=0;
  breduce4(bb,z1,z2,z3,red);
  return (bb>=16.f)?1:0;
}

// ---- prep0 (256 threads) ----
__global__ void prep0_kernel(const void* feat,
    const void* kW, const void* vW, const void* mW,
    const void* mu, const void* lsig, const void* noise,
    const void* gW, const void* gb_, const void* mg,
    const void* mb_, const void* mbias, const void* mask,
    int* flag, int* cnt, float* slot, float* gvec,
    u16* Wkb, u16* Wvb, u16* Wgb,
    float* Uvec, float* Qs, float* fg, void* out)
{
  __shared__ float redp[16];
  int bid=blockIdx.x;
  int t=threadIdx.x;
  int f=probe_f(feat, redp);
  if(bid==0 && t==0) *flag=f;
  __syncthreads();
  if(bid<P0_MISC){
    int which=bid>>5;           // 0:k 1:v 2:g
    int base=(bid&31)*2048;
    if(which==0){
      #pragma unroll
      for(int s=0;s<8;++s){ int e=base+s*256+t; Wkb[e]=f2bf(ldin(kW,e,f)); }
    } else if(which==1){
      #pragma unroll
      for(int s=0;s<8;++s){ int e=base+s*256+t; Wvb[e]=f2bf(ldin(vW,e,f)); }
    } else {
      #pragma unroll
      for(int s=0;s<8;++s){ int e=base+s*256+t; int c=e&255; Wgb[e]=f2bf(ldin(mg,c,f)*ldin(mW,e,f)); }
    }
    return;
  }
  if(bid==P0_MISC){
    if(t<16) cnt[t]=0;
    #pragma unroll
    for(int s=0;s<20;++s){ int e=s*256+t; int d=e&255;
      slot[e]=ldin(mu,d,f)+expf(ldin(lsig,d,f))*ldin(noise,e,f); }
    #pragma unroll
    for(int s=0;s<3;++s){ int e=s*256+t;
      int c=e&255, sel=e>>8;
      float v;
      if(sel==0)      v=ldin(gW,c*4+0,f)-ldin(gW,c*4+2,f);
      else if(sel==1) v=ldin(gW,c*4+1,f)-ldin(gW,c*4+3,f);
      else            v=ldin(gb_,c,f);
      gvec[e]=v;
    }
    return;
  }
  __shared__ float s_a[256], s_b[256], s_c[256];
  if(bid==P0_UQ){
    __shared__ float s_mg[256], s_mb[256];
    s_a[t]=ldin(gW,t*4+0,f)-ldin(gW,t*4+2,f);
    s_b[t]=ldin(gW,t*4+1,f)-ldin(gW,t*4+3,f);
    s_c[t]=ldin(gb_,t,f);
    s_mg[t]=ldin(mg,t,f);
    s_mb[t]=ldin(mb_,t,f);
    __syncthreads();
    float u1=0,u2=0,u3=0,gw=0,bw=0;
    if(f){
      const float4* rp=(const float4*)mW + (size_t)t*64;
      #pragma unroll 8
      for(int j=0;j<64;++j){
        float4 v4=rp[j]; int c=j*4;
        float m0=v4.x,m1=v4.y,m2=v4.z,m3=v4.w;
        float w0=s_mg[c]*m0, w1=s_mg[c+1]*m1, w2=s_mg[c+2]*m2, w3=s_mg[c+3]*m3;
        u1+=s_a[c]*w0+s_a[c+1]*w1+s_a[c+2]*w2+s_a[c+3]*w3;
        u2+=s_b[c]*w0+s_b[c+1]*w1+s_b[c+2]*w2+s_b[c+3]*w3;
        u3+=s_c[c]*w0+s_c[c+1]*w1+s_c[c+2]*w2+s_c[c+3]*w3;
        gw+=w0+w1+w2+w3;
        bw+=s_mb[c]*m0+s_mb[c+1]*m1+s_mb[c+2]*m2+s_mb[c+3]*m3;
      }
    } else {
      const bf8v* rp=(const bf8v*)((const u16*)mW + (size_t)t*256);
      #pragma unroll 8
      for(int j=0;j<32;++j){
        bf8v v8=rp[j]; int c=j*8;
        #pragma unroll
        for(int e=0;e<8;++e){
          float mwv=bf2f((u16)(unsigned short)v8[e]);
          float wg=s_mg[c+e]*mwv;
          u1+=s_a[c+e]*wg; u2+=s_b[c+e]*wg; u3+=s_c[c+e]*wg; gw+=wg;
          bw+=s_mb[c+e]*mwv;
        }
      }
    }
    Uvec[t]=u1; Uvec[256+t]=u2; Uvec[512+t]=u3; Uvec[768+t]=gw;
    Uvec[1024+t]=bw+ldin(mbias,t,f);
    float a=s_a[t], b=s_b[t], cc=s_c[t];
    float s0=a*a,s1=b*b,s2=cc*cc,s3=a*b; breduce4(s0,s1,s2,s3,redp);
    float s4=a*cc,s5=b*cc,s6=a,s7=b;     breduce4(s4,s5,s6,s7,redp);
    float s8=cc,z1=0,z2=0,z3=0;          breduce4(s8,z1,z2,z3,redp);
    if(t==0){
      Qs[0]=s0; Qs[1]=s1; Qs[2]=s2; Qs[3]=s3; Qs[4]=s4; Qs[5]=s5;
      Qs[6]=s6*(1.f/256.f); Qs[7]=s7*(1.f/256.f); Qs[8]=s8*(1.f/256.f);
    }
  } else {
    int k=bid-P0_FG;
    float sx=0,sy=0,sm=0;
    #pragma unroll
    for(int s=0;s<16;++s){
      int p=t+s*256;
      float m=ldin(mask,(size_t)k*N_+p,f);
      int i=p>>6, j=p&63;
      float x=(2*j+1)*(1.0f/64.0f)-1.0f;
      float y=(2*i+1)*(1.0f/64.0f)-1.0f;
      sx+=x*m; sy+=y*m; sm+=m;
    }
    float d=0;
    breduce4(sx,sy,sm,d,redp);
    if(t==0){
      float inv=1.0f/(sm+1e-5f);
      float fx=sx*inv, fy=sy*inv;
      fg[k*2]=fx; fg[k*2+1]=fy;
      for(int b=0;b<B_;++b){
        stout(out, 5120+(b*K_+k)*2+0, fx, f);
        stout(out, 5120+(b*K_+k)*2+1, fy, f);
      }
    }
  }
}

// ---- base: blocks [0,512): 32 rows/block, 512 threads, 32KB LDS -> 2 blocks/CU
// ---- blocks [512,532): iter-0 q projection;  [532,660): 64x64 weight transposes (bf16 out)
__global__ void __launch_bounds__(512,4) base_kernel(const int* flag, const void* feat, const void* ng, const void* nb,
    const u16* Wkb, const u16* Wvb, const u16* Wgb, const float* gvec,
    float* scal, u16* PkT, u16* Pvb,
    const float* slot, const void* qg, const void* qb_, const void* qW,
    const void* rW, const void* Wih, const void* Whh,
    u16* WqT, u16* WrT, u16* WihT, u16* WhhT,
    float* qbuf)
{
  extern __shared__ u16 smem[];          // 32 KiB dynamic
  u16* bufA = smem;                      // fnb -> vbL (32x256 bf16, swizzled)
  u16* bufB = smem + 8192;               // kbL -> Pv staging
  int t=threadIdx.x, f=*flag;
  if(blockIdx.x>=BT_TR){
    float (*tile)[65] = (float(*)[65])smem;   // 16.6KB < 32KB
    int b2=blockIdx.x-BT_TR;
    const void* src; u16* dst; int OS;
    if(b2<16){ src=qW; dst=WqT; OS=256; }
    else if(b2<32){ src=rW; dst=WrT; OS=256; b2-=16; }
    else if(b2<80){ src=Wih; dst=WihT; OS=768; b2-=32; }
    else { src=Whh; dst=WhhT; OS=768; b2-=80; }
    int r0=(b2>>2)*64, c0=(b2&3)*64;
    int lane=t&63, wv=t>>6;
    #pragma unroll
    for(int it=0;it<8;++it){
      int i=wv*8+it;
      tile[i][lane]=ldin(src,(size_t)(r0+i)*256+c0+lane,f);
    }
    __syncthreads();
    #pragma unroll
    for(int it=0;it<8;++it){
      int i=wv*8+it;
      dst[(size_t)(c0+i)*OS + r0 + lane] = f2bf(tile[lane][i]);
    }
    return;
  }
  if(blockIdx.x>=BT_QP){
    float* Lq =(float*)smem;
    float* pp =(float*)smem+256;
    float* red=(float*)smem+768;
    int bk=blockIdx.x-BT_QP;
    int tt=t&255, hh=t>>8, w=t>>6;
    float x=slot[bk*256+tt];
    float s=x, s2=x*x;
    #pragma unroll
    for(int o=32;o>0;o>>=1){ s+=__shfl_down(s,o,64); s2+=__shfl_down(s2,o,64); }
    if((t&63)==0){ red[w]=s; red[8+w]=s2; }
    __syncthreads();
    s=0; s2=0;
    #pragma unroll
    for(int i=0;i<8;++i){ s+=red[i]; s2+=red[8+i]; }
    float m=s*(1.f/512.f), v=s2*(1.f/512.f)-m*m;   // each value counted twice
    float lq=(x-m)*rsqrtf(v+EPS_)*ldin(qg,tt,f)+ldin(qb_,tt,f);
    if(hh==0) Lq[tt]=lq;
    __syncthreads();
    float acc=0; int cb=hh*128;
    if(f){
      const float4* rp=(const float4*)qW + ((size_t)tt*256+cb)/4;
      #pragma unroll 8
      for(int j=0;j<32;++j){
        float4 v4=rp[j]; int c=cb+j*4;
        acc+=Lq[c]*v4.x+Lq[c+1]*v4.y+Lq[c+2]*v4.z+Lq[c+3]*v4.w;
      }
    } else {
      const bf8v* rp=(const bf8v*)((const u16*)qW + (size_t)tt*256+cb);
      #pragma unroll 8
      for(int j=0;j<16;++j){
        bf8v v8=rp[j]; int c=cb+j*8;
        #pragma unroll
        for(int e=0;e<8;++e) acc+=Lq[c+e]*bf2f((u16)(unsigned short)v8[e]);
      }
    }
    pp[hh*256+tt]=acc;
    __syncthreads();
    if(hh==0) qbuf[bk*256+tt]=pp[tt]+pp[256+tt];
    return;
  }
  int w=t>>6, l=t&63;
  int quad=l>>4, m=l&15;
  int row0=blockIdx.x*32;
  // ---- LN: 4 rows per wave ----
  {
    float g0=ldin(ng,4*l+0,f), g1=ldin(ng,4*l+1,f), g2=ldin(ng,4*l+2,f), g3=ldin(ng,4*l+3,f);
    float b0=ldin(nb,4*l+0,f), b1=ldin(nb,4*l+1,f), b2=ldin(nb,4*l+2,f), b3=ldin(nb,4*l+3,f);
    #pragma unroll
    for(int r4=0;r4<4;++r4){
      int row=4*w+r4;
      float x0,x1,x2,x3;
      if(f){
        float4 v4=((const float4*)feat)[(size_t)(row0+row)*64+l];
        x0=v4.x; x1=v4.y; x2=v4.z; x3=v4.w;
      } else {
        ushort4 uu=((const ushort4*)feat)[(size_t)(row0+row)*64+l];
        x0=bf2f(uu.x); x1=bf2f(uu.y); x2=bf2f(uu.z); x3=bf2f(uu.w);
      }
      float s=x0+x1+x2+x3, s2=x0*x0+x1*x1+x2*x2+x3*x3;
      #pragma unroll
      for(int o=32;o>0;o>>=1){ s+=__shfl_xor(s,o,64); s2+=__shfl_xor(s2,o,64); }
      float mm=s*(1.f/256.f), inv=rsqrtf(s2*(1.f/256.f)-mm*mm+EPS_);
      ushort4 o4=make_ushort4(f2bf((x0-mm)*inv*g0+b0), f2bf((x1-mm)*inv*g1+b1),
                              f2bf((x2-mm)*inv*g2+b2), f2bf((x3-mm)*inv*g3+b3));
      *(ushort4*)&bufA[sw16(row,4*l)]=o4;
    }
  }
  __syncthreads();
  // ---- pass1: [32 x 256] @ Wk/Wv -> kbL (bufB), vbL (regs -> bufA) ----
  {
    f4v ack[2][2], acv[2][2];
    #pragma unroll
    for(int rt=0;rt<2;++rt)
      #pragma unroll
      for(int i=0;i<2;++i){ ack[rt][i]=(f4v){0.f,0.f,0.f,0.f}; acv[rt][i]=(f4v){0.f,0.f,0.f,0.f}; }
    #pragma unroll
    for(int kk=0;kk<8;++kk){
      int kcol=kk*32+quad*8;
      bf8v af[2];
      #pragma unroll
      for(int rt=0;rt<2;++rt) af[rt]=*(bf8v*)&bufA[sw16(rt*16+m,kcol)];
      #pragma unroll
      for(int i=0;i<2;++i){
        int n=w*32+16*i+m;
        bf8v bk=*(const bf8v*)(Wkb+(size_t)n*256+kcol);
        bf8v bv=*(const bf8v*)(Wvb+(size_t)n*256+kcol);
        #pragma unroll
        for(int rt=0;rt<2;++rt){
          ack[rt][i]=__builtin_amdgcn_mfma_f32_16x16x32_bf16(af[rt],bk,ack[rt][i],0,0,0);
          acv[rt][i]=__builtin_amdgcn_mfma_f32_16x16x32_bf16(af[rt],bv,acv[rt][i],0,0,0);
        }
      }
    }
    #pragma unroll
    for(int rt=0;rt<2;++rt)
      #pragma unroll
      for(int i=0;i<2;++i){
        int n=w*32+16*i+m;
        #pragma unroll
        for(int r=0;r<4;++r)
          bufB[sw16(rt*16+quad*4+r,n)]=f2bf(ack[rt][i][r]);
      }
    __syncthreads();   // all bufA (fnb) reads done
    #pragma unroll
    for(int rt=0;rt<2;++rt)
      #pragma unroll
      for(int i=0;i<2;++i){
        int n=w*32+16*i+m;
        #pragma unroll
        for(int r=0;r<4;++r)
          bufA[sw16(rt*16+quad*4+r,n)]=f2bf(acv[rt][i][r]);
      }
  }
  __syncthreads();
  // ---- scalars: 10 per row (k: bufB, v: bufA), 4 rows/wave ----
  {
    float gA0=gvec[l], gA1=gvec[l+64], gA2=gvec[l+128], gA3=gvec[l+192];
    float gB0=gvec[256+l], gB1=gvec[256+l+64], gB2=gvec[256+l+128], gB3=gvec[256+l+192];
    float gC0=gvec[512+l], gC1=gvec[512+l+64], gC2=gvec[512+l+128], gC3=gvec[512+l+192];
    for(int r4=0;r4<4;++r4){
      int row=4*w+r4;
      float k0=bf2f(bufB[sw16(row,l)]),     k1=bf2f(bufB[sw16(row,l+64)]),
            k2=bf2f(bufB[sw16(row,l+128)]), k3=bf2f(bufB[sw16(row,l+192)]);
      float x0=bf2f(bufA[sw16(row,l)]),     x1=bf2f(bufA[sw16(row,l+64)]),
            x2=bf2f(bufA[sw16(row,l+128)]), x3=bf2f(bufA[sw16(row,l+192)]);
      float v0=k0+k1+k2+k3;
      float v1=k0*k0+k1*k1+k2*k2+k3*k3;
      float v2=k0*gA0+k1*gA1+k2*gA2+k3*gA3;
      float v3=k0*gB0+k1*gB1+k2*gB2+k3*gB3;
      float v4=k0*gC0+k1*gC1+k2*gC2+k3*gC3;
      float v5=x0+x1+x2+x3;
      float v6=x0*x0+x1*x1+x2*x2+x3*x3;
      float v7=x0*gA0+x1*gA1+x2*gA2+x3*gA3;
      float v8=x0*gB0+x1*gB1+x2*gB2+x3*gB3;
      float v9=x0*gC0+x1*gC1+x2*gC2+x3*gC3;
      #pragma unroll
      for(int o=32;o>0;o>>=1){
        v0+=__shfl_down(v0,o,64); v1+=__shfl_down(v1,o,64); v2+=__shfl_down(v2,o,64);
        v3+=__shfl_down(v3,o,64); v4+=__shfl_down(v4,o,64); v5+=__shfl_down(v5,o,64);
        v6+=__shfl_down(v6,o,64); v7+=__shfl_down(v7,o,64); v8+=__shfl_down(v8,o,64);
        v9+=__shfl_down(v9,o,64);
      }
      if(l==0){
        float* sc=scal+(size_t)(row0+row)*10;
        sc[0]=v0; sc[1]=v1; sc[2]=v2; sc[3]=v3; sc[4]=v4;
        sc[5]=v5; sc[6]=v6; sc[7]=v7; sc[8]=v8; sc[9]=v9;
      }
    }
  }
  // ---- pass2: kbL/vbL @ Wg -> PkT (direct), Pv (staged via bufB) ----
  {
    f4v apk[2][2], apv[2][2];
    #pragma unroll
    for(int rt=0;rt<2;++rt)
      #pragma unroll
      for(int i=0;i<2;++i){ apk[rt][i]=(f4v){0.f,0.f,0.f,0.f}; apv[rt][i]=(f4v){0.f,0.f,0.f,0.f}; }
    #pragma unroll
    for(int kk=0;kk<8;++kk){
      int kcol=kk*32+quad*8;
      bf8v afk[2], afv[2];
      #pragma unroll
      for(int rt=0;rt<2;++rt){
        afk[rt]=*(bf8v*)&bufB[sw16(rt*16+m,kcol)];
        afv[rt]=*(bf8v*)&bufA[sw16(rt*16+m,kcol)];
      }
      #pragma unroll
      for(int i=0;i<2;++i){
        int n=w*32+16*i+m;
        bf8v bg=*(const bf8v*)(Wgb+(size_t)n*256+kcol);
        #pragma unroll
        for(int rt=0;rt<2;++rt){
          apk[rt][i]=__builtin_amdgcn_mfma_f32_16x16x32_bf16(afk[rt],bg,apk[rt][i],0,0,0);
          apv[rt][i]=__builtin_amdgcn_mfma_f32_16x16x32_bf16(afv[rt],bg,apv[rt][i],0,0,0);
        }
      }
    }
    #pragma unroll
    for(int rt=0;rt<2;++rt)
      #pragma unroll
      for(int i=0;i<2;++i){
        int d=w*32+16*i+m;
        *(ushort4*)(PkT+(size_t)d*16384+row0+rt*16+quad*4)=
          make_ushort4(f2bf(apk[rt][i][0]),f2bf(apk[rt][i][1]),f2bf(apk[rt][i][2]),f2bf(apk[rt][i][3]));
      }
    __syncthreads();   // all bufB (kbL) reads done
    #pragma unroll
    for(int rt=0;rt<2;++rt)
      #pragma unroll
      for(int i=0;i<2;++i){
        int d=w*32+16*i+m;
        #pragma unroll
        for(int r=0;r<4;++r)
          bufB[sw16(rt*16+quad*4+r,d)]=f2bf(apv[rt][i][r]);
      }
  }
  __syncthreads();
  // ---- coalesced Pvb store (4 rows/wave) ----
  #pragma unroll
  for(int r4=0;r4<4;++r4){
    int row=4*w+r4;
    ushort4 s4=*(ushort4*)&bufB[sw16(row,4*l)];
    *(ushort4*)(Pvb+(size_t)(row0+row)*256+4*l)=s4;
  }
}

// ---- fused attn (512 threads): qsc inline + logits + chunk softmax + weighted Pv partials ----
__global__ void __launch_bounds__(512) attn_kernel(const int* flag, const float* qbuf, const u16* PkT,
    const float* scal, const float* Qs, const float* Uvec, const float* fg, const void* mask,
    const u16* Pvb, float* logits, float* pmax, float* psum, float* updpart, float* sscp,
    int store_lg)
{
  __shared__ float q5[1280];
  __shared__ float un[10240];
  __shared__ float lgs[320], ivs[320], mvs[320];
  __shared__ float qs5[40], fgs[10], Qss[9], MSl[5];
  __shared__ float sred[8][5][4];
  int tid=threadIdx.x, f=*flag;
  int b=blockIdx.x>>6, ch=blockIdx.x&63;
  int w=tid>>6, l=tid&63;
  int n0=ch<<6;
  for(int p=tid;p<1280;p+=512) q5[p]=qbuf[(size_t)b*1280+p];
  if(tid<10) fgs[tid]=fg[tid];
  if(tid<9)  Qss[tid]=Qs[tid];
  __syncthreads();
  // qsc inline
  for(int p=w;p<25;p+=8){
    int k=p/5, j=p%5;
    float s=q5[k*256+l]*Uvec[j*256+l]+q5[k*256+l+64]*Uvec[j*256+l+64]
           +q5[k*256+l+128]*Uvec[j*256+l+128]+q5[k*256+l+192]*Uvec[j*256+l+192];
    #pragma unroll
    for(int o=32;o>0;o>>=1) s+=__shfl_xor(s,o,64);
    if(l==0) qs5[k*8+j]=s;
  }
  {
    int n=n0+l; size_t row=(size_t)b*N_+n;
    float dk0=0,dk1=0,dk2=0,dk3=0,dk4=0;
    int cbase=w*32;
    #pragma unroll 8
    for(int cc=0;cc<32;++cc){
      int c=cbase+cc;
      float pv=bf2f(PkT[(size_t)c*16384+row]);
      dk0+=pv*q5[c]; dk1+=pv*q5[256+c]; dk2+=pv*q5[512+c];
      dk3+=pv*q5[768+c]; dk4+=pv*q5[1024+c];
    }
    un[(w*5+0)*64+l]=dk0; un[(w*5+1)*64+l]=dk1; un[(w*5+2)*64+l]=dk2;
    un[(w*5+3)*64+l]=dk3; un[(w*5+4)*64+l]=dk4;
  }
  __syncthreads();
  if(tid<320){
    int k=tid>>6, nl=tid&63;
    float dot=0;
    #pragma unroll
    for(int j=0;j<8;++j) dot+=un[(j*5+k)*64+nl];
    int n2=n0+nl; size_t row2=(size_t)b*N_+n2;
    const float* sc=scal+row2*10;
    float rx=(2*(n2&63)+1)*(1.f/64.f)-1.f-fgs[2*k];
    float ry=(2*(n2>>6)+1)*(1.f/64.f)-1.f-fgs[2*k+1];
    float qge=rx*rx*Qss[0]+ry*ry*Qss[1]+Qss[2]+2.f*(rx*ry*Qss[3]+rx*Qss[4]+ry*Qss[5]);
    float mk=sc[0]*(1.f/256.f)+rx*Qss[6]+ry*Qss[7]+Qss[8];
    float sxk=sc[1]+2.f*(rx*sc[2]+ry*sc[3]+sc[4])+qge;
    float invK=rsqrtf(sxk*(1.f/256.f)-mk*mk+EPS_);
    float lg=invK*(dot+rx*qs5[k*8+0]+ry*qs5[k*8+1]+qs5[k*8+2]-mk*qs5[k*8+3])+qs5[k*8+4];
    float mval=ldin(mask,(size_t)k*N_+n2,f);
    lg=(mval==0.f)? -1e9f : lg*0.0625f;
    if(store_lg) logits[((size_t)(b*5+k))*N_+n2]=lg;
    lgs[tid]=lg;
    float mv=sc[5]*(1.f/256.f)+rx*Qss[6]+ry*Qss[7]+Qss[8];
    float sxv=sc[6]+2.f*(rx*sc[7]+ry*sc[8]+sc[9])+qge;
    mvs[tid]=mv;
    ivs[tid]=rsqrtf(sxv*(1.f/256.f)-mv*mv+EPS_);
  }
  __syncthreads();
  if(tid<64){
    #pragma unroll
    for(int k=0;k<5;++k){
      float v=lgs[k*64+tid];
      float M=v;
      #pragma unroll
      for(int o=32;o>0;o>>=1) M=fmaxf(M,__shfl_xor(M,o,64));
      float e=expf(v-M);
      #pragma unroll
      for(int o=32;o>0;o>>=1) e+=__shfl_xor(e,o,64);
      if(tid==0){ pmax[((size_t)(b*64+ch))*5+k]=M; psum[((size_t)(b*64+ch))*5+k]=e; MSl[k]=M; }
    }
  }
  __syncthreads();
  {
    float acc[5][4]={{0}};
    float swx[5]={0,0,0,0,0}, swy[5]={0,0,0,0,0}, sw[5]={0,0,0,0,0}, swm[5]={0,0,0,0,0};
    #pragma unroll 2
    for(int rr=0;rr<8;++rr){
      int nl=w*8+rr; int n2=n0+nl;
      size_t row=(size_t)b*N_+n2;
      uint2 pu=*(const uint2*)(Pvb+row*256+l*4);
      float px=bflo(pu.x), py=bfhi(pu.x), pz=bflo(pu.y), pw=bfhi(pu.y);
      int jx=n2&63, iy=n2>>6;
      #pragma unroll
      for(int k=0;k<5;++k){
        float wgt=expf(lgs[k*64+nl]-MSl[k])*ivs[k*64+nl];
        float rx=(2*jx+1)*(1.f/64.f)-1.f-fgs[2*k];
        float ry=(2*iy+1)*(1.f/64.f)-1.f-fgs[2*k+1];
        acc[k][0]+=wgt*px; acc[k][1]+=wgt*py; acc[k][2]+=wgt*pz; acc[k][3]+=wgt*pw;
        sw[k]+=wgt; swx[k]+=wgt*rx; swy[k]+=wgt*ry; swm[k]+=wgt*mvs[k*64+nl];
      }
    }
    #pragma unroll
    for(int k=0;k<5;++k)
      *(float4*)&un[(w*5+k)*256+l*4]=make_float4(acc[k][0],acc[k][1],acc[k][2],acc[k][3]);
    if(l==0){
      #pragma unroll
      for(int k=0;k<5;++k){ sred[w][k][0]=swx[k]; sred[w][k][1]=swy[k];
                            sred[w][k][2]=sw[k];  sred[w][k][3]=swm[k]; }
    }
  }
  __syncthreads();
  for(int p=tid;p<1280;p+=512){
    int k=p>>8, d=p&255;
    float v=0;
    #pragma unroll
    for(int j=0;j<8;++j) v+=un[(j*5+k)*256+d];
    updpart[((size_t)blockIdx.x*5+k)*256+d]=v;
  }
  if(tid<20){
    int kk=tid>>2, j=tid&3;
    float s=0;
    #pragma unroll
    for(int jj=0;jj<8;++jj) s+=sred[jj][kk][j];
    sscp[((size_t)blockIdx.x*5+kk)*4+j]=s;
  }
}

// ---- GRU (blocks 0..19) + optional vis (blocks 20..39 when do_vis) ----
__global__ void __launch_bounds__(1024) gru_kernel(const int* flag, float* slot, const float* updpart,
    const float* sscp, const float* Uvec, const float* pmax, const float* psum, const float* logits,
    const u16* WihT, const u16* WhhT, const void* bih, const void* bhh,
    const void* rg, const void* rb_, const u16* WrT, const void* rbias,
    const void* qg, const void* qb_, const u16* WqT, float* qbuf,
    int do_vis, void* out)
{
  __shared__ float u[256], h[256], sn[256];
  __shared__ float part[4][6][256];
  __shared__ float red[64];
  __shared__ float cvec[4];
  __shared__ float fch[64];
  __shared__ float MSg[2];
  int tid=threadIdx.x, t=tid&255, g=tid>>8;
  int blk=blockIdx.x;
  int f=*flag;
  if(blk>=20){
    if(!do_vis) return;
    int bk2=blk-20, k2=bk2%K_, b2=bk2/K_;
    if(tid<64){
      float pm=pmax[((size_t)(b2*64+tid))*5+k2];
      float ps=psum[((size_t)(b2*64+tid))*5+k2];
      float M=pm;
      #pragma unroll
      for(int o=32;o>0;o>>=1) M=fmaxf(M,__shfl_xor(M,o,64));
      float e=ps*expf(pm-M);
      #pragma unroll
      for(int o=32;o>0;o>>=1) e+=__shfl_xor(e,o,64);
      if(tid==0){ MSg[0]=M; MSg[1]=1.0f/e; }
    }
    __syncthreads();
    float M=MSg[0], Sinv=MSg[1];
    float a[4]; float mn=1e30f, mx=-1e30f;
    #pragma unroll
    for(int s=0;s<4;++s){
      a[s]=expf(logits[(size_t)bk2*N_+tid+s*1024]-M)*Sinv;
      mn=fminf(mn,a[s]); mx=fmaxf(mx,a[s]);
    }
    #pragma unroll
    for(int o=32;o>0;o>>=1){ mn=fminf(mn,__shfl_down(mn,o,64)); mx=fmaxf(mx,__shfl_down(mx,o,64)); }
    int wv=tid>>6;
    __syncthreads();
    if((tid&63)==0){ red[wv]=mn; red[16+wv]=mx; }
    __syncthreads();
    mn=1e30f; mx=-1e30f;
    #pragma unroll
    for(int i=0;i<16;++i){ mn=fminf(mn,red[i]); mx=fmaxf(mx,red[16+i]); }
    float inv=1.0f/(mx-mn+1e-5f);
    #pragma unroll
    for(int s=0;s<4;++s) stout(out, 5160+(size_t)bk2*N_+tid+s*1024, (a[s]-mn)*inv, f);
    return;
  }
  int bk=blk, k=bk%K_, b=bk/K_;
  if(tid<64){
    float pm=pmax[((size_t)(b*64+tid))*5+k];
    float ps=psum[((size_t)(b*64+tid))*5+k];
    float M=pm;
    #pragma unroll
    for(int o=32;o>0;o>>=1) M=fmaxf(M,__shfl_xor(M,o,64));
    float fc=expf(pm-M);
    fch[tid]=fc;
    float e=ps*fc;
    #pragma unroll
    for(int o=32;o>0;o>>=1) e+=__shfl_xor(e,o,64);
    if(tid==0){ MSg[0]=M; MSg[1]=1.0f/e; }
  }
  __syncthreads();
  float Sinv=MSg[1];
  float ua=0;
  {
    int ch0=g*16;
    #pragma unroll 4
    for(int ci=0;ci<16;++ci){ int ch=ch0+ci; ua += fch[ch]*updpart[(((size_t)(b*64+ch))*5+k)*256+t]; }
  }
  part[g][0][t]=ua;
  if(t<4){
    float s=0;
    #pragma unroll 4
    for(int ci=0;ci<16;++ci){ int ch=g*16+ci; s += fch[ch]*sscp[(((size_t)(b*64+ch))*5+k)*4+t]; }
    part[g][1][t]=s;
  }
  __syncthreads();
  if(g==0 && t<4) cvec[t]=part[0][1][t]+part[1][1][t]+part[2][1][t]+part[3][1][t];
  __syncthreads();
  if(g==0){
    float uu=part[0][0][t]+part[1][0][t]+part[2][0][t]+part[3][0][t];
    u[t]=(uu+cvec[0]*Uvec[t]+cvec[1]*Uvec[256+t]+cvec[2]*Uvec[512+t]-cvec[3]*Uvec[768+t])*Sinv
         +Uvec[1024+t];
    h[t]=slot[bk*256+t];
  }
  __syncthreads();
  float p0=0,p1=0,p2=0,p3=0,p4=0,p5=0;
  int c0=g*64;
  #pragma unroll 8
  for(int cc=0;cc<64;++cc){
    int c=c0+cc;
    float uc=u[c], hc=h[c];
    const u16* wi=WihT+(size_t)c*768+t;
    const u16* wh=WhhT+(size_t)c*768+t;
    p0+=uc*bf2f(wi[0]); p1+=uc*bf2f(wi[256]); p2+=uc*bf2f(wi[512]);
    p3+=hc*bf2f(wh[0]); p4+=hc*bf2f(wh[256]); p5+=hc*bf2f(wh[512]);
  }
  part[g][0][t]=p0; part[g][1][t]=p1; part[g][2][t]=p2;
  part[g][3][t]=p3; part[g][4][t]=p4; part[g][5][t]=p5;
  __syncthreads();
  float hn=0;
  if(g==0){
    float gi0=ldin(bih,t,f)+part[0][0][t]+part[1][0][t]+part[2][0][t]+part[3][0][t];
    float gi1=ldin(bih,256+t,f)+part[0][1][t]+part[1][1][t]+part[2][1][t]+part[3][1][t];
    float gi2=ldin(bih,512+t,f)+part[0][2][t]+part[1][2][t]+part[2][2][t]+part[3][2][t];
    float gh0=ldin(bhh,t,f)+part[0][3][t]+part[1][3][t]+part[2][3][t]+part[3][3][t];
    float gh1=ldin(bhh,256+t,f)+part[0][4][t]+part[1][4][t]+part[2][4][t]+part[3][4][t];
    float gh2=ldin(bhh,512+t,f)+part[0][5][t]+part[1][5][t]+part[2][5][t]+part[3][5][t];
    float r=1.f/(1.f+expf(-(gi0+gh0)));
    float z=1.f/(1.f+expf(-(gi1+gh1)));
    float nn=tanhf(gi2+r*gh2);
    hn=(1.f-z)*nn+z*h[t];
  }
  float s=hn, sq=hn*hn, za=0, zb=0;
  breduce4_16(s,sq,za,zb,red);
  if(g==0){
    float m=s*(1.f/256.f), var=sq*(1.f/256.f)-m*m;
    u[t]=(hn-m)*rsqrtf(var+EPS_)*ldin(rg,t,f)+ldin(rb_,t,f);
  }
  __syncthreads();
  float pr=0;
  #pragma unroll 8
  for(int cc=0;cc<64;++cc){ int c=c0+cc; pr+=u[c]*bf2f(WrT[(size_t)c*256+t]); }
  part[g][0][t]=pr;
  __syncthreads();
  if(g==0){
    float acc=ldin(rbias,t,f)+h[t]+part[0][0][t]+part[1][0][t]+part[2][0][t]+part[3][0][t];
    slot[bk*256+t]=acc;
    stout(out, (size_t)bk*256+t, acc, f);
    sn[t]=acc;
  }
  __syncthreads();
  float xs=(g==0)? sn[t]:0.f;
  float xq=xs*xs, zc=0, zd=0;
  breduce4_16(xs,xq,zc,zd,red);
  if(g==0){
    float m=xs*(1.f/256.f), var=xq*(1.f/256.f)-m*m;
    u[t]=(sn[t]-m)*rsqrtf(var+EPS_)*ldin(qg,t,f)+ldin(qb_,t,f);
  }
  __syncthreads();
  float pq=0;
  #pragma unroll 8
  for(int cc=0;cc<64;++cc){ int c=c0+cc; pq+=u[c]*bf2f(WqT[(size_t)c*256+t]); }
  part[g][0][t]=pq;
  __syncthreads();
  if(g==0){
    float qv=part[0][0][t]+part[1][0][t]+part[2][0][t]+part[3][0][t];
    qbuf[bk*256+t]=qv;
  }
}

extern "C" void kernel_launch(void* const* d_in, const int* in_sizes, int n_in,
                              void* d_out, int out_size, void* d_ws, size_t ws_size,
                              hipStream_t stream)
{
  const void* feat =d_in[0];  const void* mask =d_in[1];  const void* noise=d_in[2];
  const void* mu   =d_in[3];  const void* lsig =d_in[4];  const void* ng   =d_in[5];
  const void* nb   =d_in[6];  const void* gW   =d_in[7];  const void* gb_  =d_in[8];
  const void* kW   =d_in[9];  const void* vW   =d_in[10]; const void* mg   =d_in[11];
  const void* mb_  =d_in[12]; const void* mW   =d_in[13]; const void* mbias=d_in[14];
  const void* qg   =d_in[15]; const void* qb_  =d_in[16]; const void* qW   =d_in[17];
  const void* Wih  =d_in[18]; const void* Whh  =d_in[19]; const void* bih  =d_in[20];
  const void* bhh  =d_in[21]; const void* rg   =d_in[22]; const void* rb_  =d_in[23];
  const void* rW   =d_in[24]; const void* rbias=d_in[25];

  char* p=(char*)d_ws;
  auto alloc=[&](size_t bytes)->char*{ char* r=p; p+=(bytes+255)&~(size_t)255; return r; };
  int*   flag   =(int*)  alloc(256);
  int*   cnt    =(int*)  alloc(2048);
  float* fg     =(float*)alloc(64);
  float* slot   =(float*)alloc(5120*4);
  float* qbuf   =(float*)alloc(5120*4);
  float* logits =(float*)alloc((size_t)81920*4);
  float* pmax   =(float*)alloc(1280*4);
  float* psum   =(float*)alloc(1280*4);
  float* updpart=(float*)alloc((size_t)256*5*256*4);
  float* sscp   =(float*)alloc((size_t)256*5*4*4);
  u16*   WqT    =(u16*)  alloc((size_t)65536*2);
  u16*   WrT    =(u16*)  alloc((size_t)65536*2);
  u16*   WihT   =(u16*)  alloc((size_t)196608*2);
  u16*   WhhT   =(u16*)  alloc((size_t)196608*2);
  float* gvec   =(float*)alloc(768*4);
  float* Uvec   =(float*)alloc(1280*4);
  float* Qs     =(float*)alloc(64);
  float* scal   =(float*)alloc((size_t)163840*4);
  u16*   Wkb    =(u16*)  alloc((size_t)65536*2);
  u16*   Wvb    =(u16*)  alloc((size_t)65536*2);
  u16*   Wgb    =(u16*)  alloc((size_t)65536*2);
  u16*   PkT    =(u16*)  alloc((size_t)16384*256*2);
  u16*   Pvb    =(u16*)  alloc((size_t)16384*256*2);

  prep0_kernel<<<P0_GRID,256,0,stream>>>(feat,kW,vW,mW,mu,lsig,noise,gW,gb_,mg,
                                         mb_,mbias,mask,
                                         flag,cnt,slot,gvec,Wkb,Wvb,Wgb,
                                         Uvec,Qs,fg,d_out);
  base_kernel<<<BT_GRID,512,32768,stream>>>(flag,feat,ng,nb,Wkb,Wvb,Wgb,gvec,scal,PkT,Pvb,
                                            slot,qg,qb_,qW,rW,Wih,Whh,
                                            WqT,WrT,WihT,WhhT,qbuf);
  for(int it=0; it<IT_; ++it){
    attn_kernel<<<B_*64,512,0,stream>>>(flag,qbuf,PkT,scal,Qs,Uvec,fg,mask,Pvb,
                                        logits,pmax,psum,updpart,sscp,(it==IT_-1)?1:0);
    int nb_g = (it==IT_-1)? 40 : 20;
    gru_kernel<<<nb_g,1024,0,stream>>>(flag,slot,updpart,sscp,Uvec,pmax,psum,logits,
                                       WihT,WhhT,bih,bhh,rg,rb_,WrT,rbias,
                                       qg,qb_,WqT,qbuf,(it==IT_-1)?1:0,d_out);
  }
}